// Round 12
// baseline (2959.833 us; speedup 1.0000x reference)
//
#include <hip/hip_runtime.h>
#include <hip/hip_bf16.h>
#include <cstdint>
#include <cstddef>

typedef __bf16 bf16;
typedef __bf16 bf16x2 __attribute__((ext_vector_type(2)));
typedef __bf16 bf16x4 __attribute__((ext_vector_type(4)));
typedef __bf16 bf16x8 __attribute__((ext_vector_type(8)));
typedef float f32x4 __attribute__((ext_vector_type(4)));

static_assert(sizeof(bf16x8) == 16, "bf16x8 must be 16B");

#define NE 16384   // E
#define ND 1024    // D
#define NA 512     // A
#define NM 2048    // M
#define NH 3
#define NRES 3
#define ESH 14     // log2(NE)

// ---------------------------------------------------------------------------
// async global->LDS, 16B per lane (wave-uniform LDS base + lane*16 implicit)
__device__ __forceinline__ void async_ld16(const bf16* g, bf16* l) {
  __builtin_amdgcn_global_load_lds(
      (__attribute__((address_space(1))) void*)(void*)g,
      (__attribute__((address_space(3))) void*)(void*)l, 16, 0, 0);
}

template <int N>
__device__ __forceinline__ void vm_wait() {
  asm volatile("s_waitcnt vmcnt(%0)" ::"n"(N) : "memory");
}
__device__ __forceinline__ void lgkm0() {
  asm volatile("s_waitcnt lgkmcnt(0)" ::: "memory");
}
__device__ __forceinline__ void bar() {
  asm volatile("s_barrier" ::: "memory");
}
#define PIN() __builtin_amdgcn_sched_barrier(0)

// ---------------------------------------------------------------------------
// 256x256-tile bf16 GEMM, 3-barriers-per-K-tile (R8 core, FROZEN: best of 7
// schedule variants). C = A[M,K] @ B^T[N,K], fp32 accum via
// v_mfma_f32_16x16x32_bf16. 512 threads = 8 waves (2M x 4N), 128x64 C/wave.
//
// R12: LN FUSION. LN(x)@Wr = rstd_m*( x@(g.Wr) - mu_m*sgW[n] ) + bWbr[n],
// sgW[n] = sum_k g[k]Wr[k][n], bWbr[n] = sum_k b[k]Wr[k][n] + br[n]
// (precomputed). MODE 1 consumes RAW mbuf as A vs g-folded WrT and applies
// the per-row affine in the epilogue using stats (sum y, sum y^2) that the
// PRODUCER GEMM's epilogue (W0 / previous ResNet) accumulated via 16-lane
// shfl_xor reduce + atomicAdd into stats[inst][NE][2] f32 (zeroed upfront;
// stream order = producer->consumer visibility). Deletes all 9 LN launches
// and the xnb buffer.
//
// Sync structure (verified R7): 3 barriers/tile —
//   barA after fb1+fa-MQ1 reads drain -> legalizes staging units[1](t+2)
//   barB after counted vm_wait<8> (retires tile t+1; t+2's 8 stay in flight)
//   barC after prefetch reads drain -> legalizes next tile's units[0] staging
//
// LDS per matrix: [2 bufs][2 units][128 rows][64 cols] bf16, 128 KiB total.
// Unit u holds global rows (lr>>6)*128 + u*64 + (lr&63). Chunk swizzle:
// logical chunk cc of row r at slot cc^(r&7); global source pre-swizzled.
// Block mapping: n-major (bid%nbx) -> A panels L2-resident.
// C-column mapping: n = (wn>>1)*128 + NQ*64 + (wn&1)*32 + j*16 + l15
//
// MODE 0: C_bf16 = acc + bias[n]; optional split-output (fused K/V); optional
//         stats_out accumulation (W0).
// MODE 1: y = addb[m,n] + relu(rstd*(acc - mu*bias[n]) + lnbb[n]) in-place;
//         bias==sgW, lnbb==bWbr, stats_in = producer stats; optional stats_out.
// MODE 2: C_bf16[m&(NE-1), hidx*coloff+n] = acc+bias[n]+addb[m,n] (-> cat)
// MODE 3: C_f32[m,n] += acc                               (final += Q-K)

#define LDA_H(KS, BUF, MQ)                                                    \
  {                                                                           \
    const int ab_ = ((BUF)*2 + (MQ)) * 8192 + aOff;                           \
    const int co_ = (c0 ^ ((KS) << 2)) * 8;                                   \
    _Pragma("unroll") for (int i = 0; i < 4; ++i)                             \
        fa[KS][i] = *(const bf16x8*)&lA[ab_ + i * 1024 + co_];                \
  }

#define LDB_H(DST, KS, BUF, NQ)                                               \
  {                                                                           \
    const int bb_ = ((BUF)*2 + (NQ)) * 8192 + bOff;                           \
    const int co_ = (c0 ^ ((KS) << 2)) * 8;                                   \
    _Pragma("unroll") for (int j = 0; j < 2; ++j)                             \
        DST[KS][j] = *(const bf16x8*)&lB[bb_ + j * 1024 + co_];               \
  }

#define MFMA_H(KS, MQ, NQ, FB)                                                \
  __builtin_amdgcn_s_setprio(1);                                              \
  _Pragma("unroll") for (int i = 0; i < 4; ++i)                               \
  _Pragma("unroll") for (int j = 0; j < 2; ++j)                               \
      acc[(MQ)*4 + i][(NQ)*2 + j] = __builtin_amdgcn_mfma_f32_16x16x32_bf16(  \
          fa[KS][i], FB[KS][j], acc[(MQ)*4 + i][(NQ)*2 + j], 0, 0, 0);        \
  __builtin_amdgcn_s_setprio(0);

template <int MODE>
__global__ __launch_bounds__(512, 2) void gemm_kernel(
    const bf16* __restrict__ A, const bf16* __restrict__ B,
    const float* __restrict__ bias, void* __restrict__ Cv,
    const bf16* __restrict__ addb, int K, int ldc, int coloff, int addld,
    int nbx, int hsh, long long bstr, int bistr,
    const float* __restrict__ lnbb, const float* __restrict__ stats_in,
    float* __restrict__ stats_out) {
  __shared__ bf16 lA[32768];  // [buf][unit][128][64]
  __shared__ bf16 lB[32768];

  // T1: XCD-aware block swizzle (all grids here are multiples of 8)
  const int nwg = gridDim.x;
  int bid = blockIdx.x;
  if ((nwg & 7) == 0) bid = (bid & 7) * (nwg >> 3) + (bid >> 3);
  const int n0 = (bid % nbx) * 256;
  const int m0 = (bid / nbx) * 256;

  // head-batched addressing (used only by the Wms launch)
  const int hidx = hsh ? (m0 >> hsh) : 0;
  if (hsh) {
    B += (size_t)hidx * (size_t)bstr;
    bias += (size_t)hidx * (size_t)bistr;
  }

  const int tid = threadIdx.x;
  const int wv = tid >> 6, ln = tid & 63;
  const int wm = wv >> 2, wn = wv & 3;  // 2x4 waves, each 128x64 of C

  // staging lane geometry: lane covers row (wv*8 + ln>>3), slot (ln&7),
  // fetching logical chunk (ln&7)^(ln>>3)  [pre-swizzled source]
  const int rowq = wv * 8 + (ln >> 3);
  const int colo = ((ln & 7) ^ (ln >> 3)) * 8;
  const bf16* gA = A + (size_t)(m0 + rowq) * K + colo;
  const bf16* gB = B + (size_t)(n0 + rowq) * K + colo;

  auto stageA = [&](int bf, int u, int t) {
#pragma unroll
    for (int r = 0; r < 2; ++r)
      async_ld16(gA + (size_t)(r * 128 + u * 64) * K + t * 64,
                 &lA[((bf * 2 + u) * 128 + r * 64 + wv * 8) * 64]);
  };
  auto stageB = [&](int bf, int u, int t) {
#pragma unroll
    for (int r = 0; r < 2; ++r)
      async_ld16(gB + (size_t)(r * 128 + u * 64) * K + t * 64,
                 &lB[((bf * 2 + u) * 128 + r * 64 + wv * 8) * 64]);
  };

  // fragment read geometry (16x16x32: A row = ln&15, k-chunk = ln>>4)
  const int l15 = ln & 15;
  const int aOff = (wm * 64 + l15) * 64;  // unit-local row * 64
  const int bOff = (wn * 32 + l15) * 64;
  const int c0 = (ln >> 4) ^ (ln & 7);    // swizzled chunk slot, ks=0

  f32x4 acc[8][4] = {};
  bf16x8 fa[2][4], fb0[2][2], fb1[2][2];

  const int nt = K >> 6;

  // prologue: stage tiles 0 and 1 fully; vm_wait<8> retires tile 0 (leaves
  // tile 1's 8 in flight); prefetch F(0)'s leading frags (fa-MQ0, fb0);
  // lgkm0+bar so tile0's unit[0] staging is >=1 bar after these reads.
  stageA(0, 0, 0); stageA(0, 1, 0); stageB(0, 0, 0); stageB(0, 1, 0);
  stageA(1, 0, 1); stageA(1, 1, 1); stageB(1, 0, 1); stageB(1, 1, 1);
  vm_wait<8>();
  bar();
  LDA_H(0, 0, 0); LDA_H(1, 0, 0); LDB_H(fb0, 0, 0, 0); LDB_H(fb0, 1, 0, 0);
  lgkm0();
  bar();

  for (int t = 0; t < nt; ++t) {
    const int buf = t & 1, nb = buf ^ 1;
    const bool s1 = t + 1 < nt, s2 = t + 2 < nt;
    // ---- Half1: quadrants (0,0),(0,1) ----
    if (s2) { stageB(buf, 0, t + 2); stageA(buf, 0, t + 2); }
    PIN();
    LDB_H(fb1, 0, buf, 1); LDB_H(fb1, 1, buf, 1);
    PIN();
    MFMA_H(0, 0, 0, fb0);
    MFMA_H(1, 0, 0, fb0);
    MFMA_H(0, 0, 1, fb1);
    PIN();
    LDA_H(0, buf, 1);            // fa[0] <- MQ1-ks0 (MQ0-ks0 dead)
    PIN();
    MFMA_H(1, 0, 1, fb1);
    PIN();
    LDA_H(1, buf, 1);            // fa[1] <- MQ1-ks1
    lgkm0();
    bar();                        // barA
    // ---- Half2a: quadrant (1,1); stage units[1]; retire t+1 ----
    if (s2) { stageB(buf, 1, t + 2); stageA(buf, 1, t + 2); }
    PIN();
    MFMA_H(0, 1, 1, fb1);
    MFMA_H(1, 1, 1, fb1);
    if (s2) { vm_wait<8>(); } else if (s1) { vm_wait<0>(); }
    bar();                        // barB (publishes tile t+1)
    // ---- Half2b: quadrant (1,0); prefetch F(t+1) leading frags ----
    MFMA_H(0, 1, 0, fb0);
    PIN();
    if (s1) { LDB_H(fb0, 0, nb, 0); LDA_H(0, nb, 0); }
    PIN();
    MFMA_H(1, 1, 0, fb0);
    PIN();
    if (s1) { LDB_H(fb0, 1, nb, 0); LDA_H(1, nb, 0); }
    lgkm0();
    bar();                        // barC
  }

  // epilogue: 16x16 C/D layout col = ln&15, row = (ln>>4)*4 + r.
  const int r4 = (ln >> 4) * 4;
  const int nbase = n0 + (wn >> 1) * 128 + (wn & 1) * 32 + l15;
#pragma unroll
  for (int mi = 0; mi < 8; ++mi) {
#pragma unroll
    for (int r = 0; r < 4; ++r) {
      const int m = m0 + wm * 128 + mi * 16 + r4 + r;
      float mu = 0.f, rstd = 0.f;
      if constexpr (MODE == 1) {
        const float2 st = *(const float2*)&stats_in[2 * m];
        mu = st.x * (1.f / NM);
        const float var = st.y * (1.f / NM) - mu * mu;
        rstd = rsqrtf(fmaxf(var, 0.f) + 1e-5f);
      }
      float s = 0.f, sq = 0.f;
#pragma unroll
      for (int ni = 0; ni < 4; ++ni) {
        const int n = nbase + (ni >> 1) * 64 + (ni & 1) * 16;
        float v = acc[mi][ni][r];
        if constexpr (MODE == 0) {
          v += bias[n];
          size_t idx = (size_t)m * ldc + n;
          if (coloff && n >= coloff) idx += (size_t)addld;  // split output
          ((bf16*)Cv)[idx] = (bf16)v;
          s += v; sq += v * v;
        } else if constexpr (MODE == 1) {
          v = rstd * (v - mu * bias[n]) + lnbb[n];  // bias == sgW here
          const float prev = (float)addb[(size_t)m * addld + n];
          const float y = prev + fmaxf(v, 0.f);
          ((bf16*)Cv)[(size_t)m * ldc + n] = (bf16)y;
          s += y; sq += y * y;
        } else if constexpr (MODE == 2) {
          v += bias[n];
          v += (float)addb[(size_t)m * addld + n];
          const int mloc = hsh ? (m & ((1 << hsh) - 1)) : m;
          ((bf16*)Cv)[(size_t)mloc * ldc + hidx * coloff + n] = (bf16)v;
        } else {
          float* C = (float*)Cv;
          const size_t idx = (size_t)m * ldc + n;
          C[idx] = C[idx] + v;
        }
      }
      if constexpr (MODE <= 1) {
        if (stats_out) {
#pragma unroll
          for (int o = 1; o < 16; o <<= 1) {
            s += __shfl_xor(s, o, 64);
            sq += __shfl_xor(sq, o, 64);
          }
          if (l15 == 0) {
            atomicAdd(&stats_out[2 * m], s);
            atomicAdd(&stats_out[2 * m + 1], sq);
          }
        }
      }
    }
  }
}

template <int MODE>
static void launch_gemm(hipStream_t s, const bf16* A, const bf16* B,
                        const float* bias, void* C, const bf16* addb, int M,
                        int N, int K, int ldc, int coloff, int addld,
                        int hsh = 0, long long bstr = 0, int bistr = 0,
                        const float* lnbb = nullptr,
                        const float* stats_in = nullptr,
                        float* stats_out = nullptr) {
  const int nbx = N / 256;
  gemm_kernel<MODE><<<dim3(nbx * (M / 256)), 512, 0, s>>>(
      A, B, bias, C, addb, K, ldc, coloff, addld, nbx, hsh, bstr, bistr,
      lnbb, stats_in, stats_out);
}

// ---------------------------------------------------------------------------
// fp32 [K,N] -> bf16 [N,K] transpose-convert, 32x32 tiles, batched over z.
// Optional per-k scale (scale[z*K + k]) for LN g-folding into WrT.
__global__ void transpose_cvt(const float* __restrict__ src,
                              bf16* __restrict__ dst, int K, int N,
                              const float* __restrict__ scale) {
  __shared__ float t[32][33];
  const int z = blockIdx.z;
  const size_t zo = (size_t)z * K * N;
  src += zo;
  dst += zo;
  const int n = blockIdx.x * 32 + threadIdx.x;
  const int kb = blockIdx.y * 32;
#pragma unroll
  for (int i = 0; i < 4; ++i) {
    const int k = kb + threadIdx.y + i * 8;
    t[threadIdx.y + i * 8][threadIdx.x] = src[(size_t)k * N + n];
  }
  __syncthreads();
  const float sc = scale ? scale[(size_t)z * K + kb + threadIdx.x] : 1.f;
#pragma unroll
  for (int i = 0; i < 4; ++i) {
    const int nn = blockIdx.x * 32 + threadIdx.y + i * 8;
    dst[(size_t)nn * K + kb + threadIdx.x] =
        (bf16)(t[threadIdx.x][threadIdx.y + i * 8] * sc);
  }
}

// ---------------------------------------------------------------------------
// sgW[hj][n] = sum_k g[hj][k]*Wr[hj][k][n]; bWbr[hj][n] = sum_k b*Wr + br[n]
__global__ void lnfold_kernel(const float* __restrict__ Wr,
                              const float* __restrict__ g,
                              const float* __restrict__ b,
                              const float* __restrict__ br,
                              float* __restrict__ sgW,
                              float* __restrict__ bWbr) {
  const int hj = blockIdx.y;
  const int n = blockIdx.x * 256 + threadIdx.x;
  const float* W = Wr + (size_t)hj * NM * NM;
  float sg = 0.f, sb = 0.f;
  for (int k = 0; k < NM; ++k) {
    const float w = W[(size_t)k * NM + n];
    sg += g[hj * NM + k] * w;
    sb += b[hj * NM + k] * w;
  }
  sgW[hj * NM + n] = sg;
  bWbr[hj * NM + n] = sb + br[hj * NM + n];
}

// ---------------------------------------------------------------------------
__global__ void zerof_kernel(float* __restrict__ p, int n) {
  const int i = blockIdx.x * 256 + threadIdx.x;
  if (i < n) p[i] = 0.f;
}

// ---------------------------------------------------------------------------
// concat two fp32 vectors (bk|bv) -> dst
__global__ void concat2_kernel(const float* __restrict__ a,
                               const float* __restrict__ b,
                               float* __restrict__ dst, int na) {
  const int i = blockIdx.x * 256 + threadIdx.x;
  dst[i] = (i < na) ? a[i] : b[i - na];
}

// ---------------------------------------------------------------------------
// Q = normalize(h)[src], K = rep[dst]; emit bf16 Q,K and fp32 (Q-K) -> d_out
__global__ __launch_bounds__(256) void gather_kernel(
    const float* __restrict__ h, const float* __restrict__ rep,
    const int* __restrict__ src, const int* __restrict__ dst,
    bf16* __restrict__ Qb, bf16* __restrict__ Kb, float* __restrict__ qk) {
  __shared__ float sm[4];
  const int e = blockIdx.x, tid = threadIdx.x;
  const int sr = src[e], dr = dst[e];
  const float4 hv = ((const float4*)(h + (size_t)sr * ND))[tid];
  float ss = hv.x * hv.x + hv.y * hv.y + hv.z * hv.z + hv.w * hv.w;
#pragma unroll
  for (int o = 32; o > 0; o >>= 1) ss += __shfl_down(ss, o, 64);
  if ((tid & 63) == 0) sm[tid >> 6] = ss;
  __syncthreads();
  const float tot = sm[0] + sm[1] + sm[2] + sm[3];
  const float inv = 1.f / fmaxf(sqrtf(tot), 1e-12f);
  const float4 rv = ((const float4*)(rep + (size_t)dr * ND))[tid];
  const float q0 = hv.x * inv, q1 = hv.y * inv, q2 = hv.z * inv,
              q3 = hv.w * inv;
  const size_t base = (size_t)e * ND + tid * 4;
  bf16x4 qv;
  qv[0] = (bf16)q0; qv[1] = (bf16)q1; qv[2] = (bf16)q2; qv[3] = (bf16)q3;
  *(bf16x4*)(Qb + base) = qv;
  bf16x4 kv;
  kv[0] = (bf16)rv.x; kv[1] = (bf16)rv.y; kv[2] = (bf16)rv.z;
  kv[3] = (bf16)rv.w;
  *(bf16x4*)(Kb + base) = kv;
  *(float4*)(qk + base) =
      make_float4(q0 - rv.x, q1 - rv.y, q2 - rv.z, q3 - rv.w);
}

// ---------------------------------------------------------------------------
// attn = softmax(Qp*Kp/sqrt(A), axis=-1) * Vp   (per row of 512)
// Qp/Kp/Vp are [E][H*A]; attn out is [h][E][A]. grid = (E, H).
__global__ __launch_bounds__(256) void softmax_kernel(
    const bf16* __restrict__ Qp, const bf16* __restrict__ Kp,
    const bf16* __restrict__ Vp, bf16* __restrict__ attn) {
  __shared__ float sm[4];
  const int tid = threadIdx.x;
  const int e = blockIdx.x, hh = blockIdx.y;
  const size_t base = (size_t)e * (NH * NA) + (size_t)hh * NA + 2 * tid;
  const bf16x2 q = *(const bf16x2*)(Qp + base);
  const bf16x2 k = *(const bf16x2*)(Kp + base);
  const bf16x2 v = *(const bf16x2*)(Vp + base);
  const float sc = 0.044194173824159216f;  // 1/sqrt(512)
  const float s0 = (float)q[0] * (float)k[0] * sc;
  const float s1 = (float)q[1] * (float)k[1] * sc;
  float mx = fmaxf(s0, s1);
#pragma unroll
  for (int o = 32; o > 0; o >>= 1) mx = fmaxf(mx, __shfl_down(mx, o, 64));
  if ((tid & 63) == 0) sm[tid >> 6] = mx;
  __syncthreads();
  mx = fmaxf(fmaxf(sm[0], sm[1]), fmaxf(sm[2], sm[3]));
  __syncthreads();
  const float p0 = expf(s0 - mx), p1 = expf(s1 - mx);
  float ssum = p0 + p1;
#pragma unroll
  for (int o = 32; o > 0; o >>= 1) ssum += __shfl_down(ssum, o, 64);
  if ((tid & 63) == 0) sm[tid >> 6] = ssum;
  __syncthreads();
  const float inv = 1.f / (sm[0] + sm[1] + sm[2] + sm[3]);
  bf16x2 r;
  r[0] = (bf16)(p0 * inv * (float)v[0]);
  r[1] = (bf16)(p1 * inv * (float)v[1]);
  const size_t obase = (size_t)hh * NE * NA + (size_t)e * NA + 2 * tid;
  *(bf16x2*)(attn + obase) = r;
}

// ---------------------------------------------------------------------------
extern "C" void kernel_launch(void* const* d_in, const int* in_sizes, int n_in,
                              void* d_out, int out_size, void* d_ws,
                              size_t ws_size, hipStream_t stream) {
  const float* h    = (const float*)d_in[0];
  const float* rep  = (const float*)d_in[1];
  const int* src    = (const int*)d_in[2];
  const int* dst    = (const int*)d_in[3];
  const float* Wq   = (const float*)d_in[4];
  const float* bq   = (const float*)d_in[5];
  const float* Wk   = (const float*)d_in[6];
  const float* bk   = (const float*)d_in[7];
  const float* Wv   = (const float*)d_in[8];
  const float* bv   = (const float*)d_in[9];
  const float* W0   = (const float*)d_in[10];
  const float* b0   = (const float*)d_in[11];
  const float* Wr   = (const float*)d_in[12];
  const float* br   = (const float*)d_in[13];
  const float* g_ln = (const float*)d_in[14];
  const float* b_ln = (const float*)d_in[15];
  const float* Wms  = (const float*)d_in[16];
  const float* bms  = (const float*)d_in[17];
  const float* Wuas = (const float*)d_in[18];
  float* out = (float*)d_out;

  bf16* ws = (bf16*)d_ws;
  size_t off = 0;
  auto alloc = [&](size_t n) {
    bf16* p = ws + off;
    off += n;
    return p;
  };
  bf16* WqT   = alloc((size_t)NH * NA * ND);       // [h*512][1024]
  bf16* WkT   = alloc((size_t)NH * NA * ND);       // contiguous with WvT!
  bf16* WvT   = alloc((size_t)NH * NA * ND);
  bf16* W0T   = alloc((size_t)NH * NM * NA);       // [h][2048][512]
  bf16* WrT   = alloc((size_t)NH * NRES * NM * NM);// [h*3+j][2048][2048] g-folded
  bf16* WmsT  = alloc((size_t)NH * NA * NM);       // [h][512][2048]
  bf16* WuasT = alloc((size_t)ND * NH * NA);       // [1024][1536]
  bf16* Qb    = alloc((size_t)NE * ND);
  bf16* Kb    = alloc((size_t)NE * ND);
  bf16* Qp    = alloc((size_t)NE * NH * NA);       // [E][1536]; reused as cat
  bf16* Kp    = alloc((size_t)NE * NH * NA);       // Kp then Vp contiguous
  bf16* Vp    = alloc((size_t)NE * NH * NA);
  bf16* attn  = alloc((size_t)NH * NE * NA);       // [h][E][512]
  bf16* mbuf3 = alloc((size_t)NH * NE * NM);       // [h][E][2048] (persists)
  float* cbias  = (float*)alloc(2 * (size_t)NH * NA * 2);      // fp32[3072]
  float* sgW    = (float*)alloc((size_t)NH * NRES * NM * 2);   // fp32[9][2048]
  float* bWbr   = (float*)alloc((size_t)NH * NRES * NM * 2);   // fp32[9][2048]
  float* stats9 = (float*)alloc((size_t)9 * NE * 2 * 2);       // fp32[9][NE][2]
  bf16* cat   = Qp;                                // alias: Qp dead after softmax
  if (ws_size < off * sizeof(bf16)) return;  // workspace too small: bail

  const dim3 tb(32, 8);
  transpose_cvt<<<dim3(NA / 32, ND / 32, NH), tb, 0, stream>>>(Wq, WqT, ND, NA,
                                                               nullptr);
  transpose_cvt<<<dim3(NA / 32, ND / 32, NH), tb, 0, stream>>>(Wk, WkT, ND, NA,
                                                               nullptr);
  transpose_cvt<<<dim3(NA / 32, ND / 32, NH), tb, 0, stream>>>(Wv, WvT, ND, NA,
                                                               nullptr);
  transpose_cvt<<<dim3(NM / 32, NA / 32, NH), tb, 0, stream>>>(W0, W0T, NA, NM,
                                                               nullptr);
  // WrT with LN gamma folded in: WrT[n][k] = Wr[k][n] * g_ln[k]
  transpose_cvt<<<dim3(NM / 32, NM / 32, NH * NRES), tb, 0, stream>>>(
      Wr, WrT, NM, NM, g_ln);
  transpose_cvt<<<dim3(NA / 32, NM / 32, NH), tb, 0, stream>>>(Wms, WmsT, NM,
                                                               NA, nullptr);
  transpose_cvt<<<dim3(ND / 32, (NH * NA) / 32, 1), tb, 0, stream>>>(
      Wuas, WuasT, NH * NA, ND, nullptr);
  concat2_kernel<<<(2 * NH * NA) / 256, 256, 0, stream>>>(bk, bv, cbias,
                                                          NH * NA);
  lnfold_kernel<<<dim3(NM / 256, NH * NRES), 256, 0, stream>>>(
      Wr, g_ln, b_ln, br, sgW, bWbr);
  zerof_kernel<<<(9 * NE * 2) / 256, 256, 0, stream>>>(stats9, 9 * NE * 2);

  gather_kernel<<<NE, 256, 0, stream>>>(h, rep, src, dst, Qb, Kb, out);

  // Q projection: N = H*A = 1536
  launch_gemm<0>(stream, Qb, WqT, bq, Qp, nullptr, NE, NH * NA, ND, NH * NA,
                 0, 0);
  // fused K+V projection: N = 3072 (B = [WkT;WvT] contiguous), split output:
  // n<1536 -> Kp[m*1536+n], n>=1536 -> Vp[m*1536+n-1536] = +(NE-1)*1536
  launch_gemm<0>(stream, Kb, WkT, cbias, Kp, nullptr, NE, 2 * NH * NA, ND,
                 NH * NA, NH * NA, (NE - 1) * NH * NA);
  softmax_kernel<<<dim3(NE, NH), 256, 0, stream>>>(Qp, Kp, Vp, attn);

  // per-head MLP chain with fused LN (stats produced by predecessor epilogue)
  for (int hh = 0; hh < NH; ++hh) {
    const bf16* attn_h = attn + (size_t)hh * NE * NA;
    bf16* mbuf_h = mbuf3 + (size_t)hh * NE * NM;
    float* S[3] = {stats9 + (size_t)(hh * 3 + 0) * NE * 2,
                   stats9 + (size_t)(hh * 3 + 1) * NE * 2,
                   stats9 + (size_t)(hh * 3 + 2) * NE * 2};
    launch_gemm<0>(stream, attn_h, W0T + (size_t)hh * NM * NA, b0 + hh * NM,
                   mbuf_h, nullptr, NE, NM, NA, NM, 0, 0, 0, 0, 0, nullptr,
                   nullptr, S[0]);
    for (int j = 0; j < NRES; ++j) {
      const int hj = hh * NRES + j;
      launch_gemm<1>(stream, mbuf_h, WrT + (size_t)hj * NM * NM,
                     sgW + (size_t)hj * NM, mbuf_h, mbuf_h, NE, NM, NM, NM, 0,
                     NM, 0, 0, 0, bWbr + (size_t)hj * NM, S[j],
                     j + 1 < NRES ? S[j + 1] : nullptr);
    }
  }
  // head-batched Wms: M = 3E -> 384 blocks
  // cat[e][h*512+n] = mbuf3[h][e][:] @ WmsT[h] + bms[h] + attn[h][e][n]
  launch_gemm<2>(stream, mbuf3, WmsT, bms, cat, attn, NH * NE, NA, NM,
                 NH * NA, NA, NA, ESH, (long long)NA * NM, NA);

  launch_gemm<3>(stream, cat, WuasT, nullptr, out, nullptr, NE, ND, NH * NA,
                 ND, 0, 0);
}

// Round 13
// 2614.767 us; speedup vs baseline: 1.1320x; 1.1320x over previous
//
#include <hip/hip_runtime.h>
#include <hip/hip_bf16.h>
#include <cstdint>
#include <cstddef>

typedef __bf16 bf16;
typedef __bf16 bf16x2 __attribute__((ext_vector_type(2)));
typedef __bf16 bf16x4 __attribute__((ext_vector_type(4)));
typedef __bf16 bf16x8 __attribute__((ext_vector_type(8)));
typedef float f32x4 __attribute__((ext_vector_type(4)));

static_assert(sizeof(bf16x8) == 16, "bf16x8 must be 16B");

#define NE 16384   // E
#define ND 1024    // D
#define NA 512     // A
#define NM 2048    // M
#define NH 3
#define NRES 3
#define ESH 14     // log2(NE)

// ---------------------------------------------------------------------------
// async global->LDS, 16B per lane (wave-uniform LDS base + lane*16 implicit)
__device__ __forceinline__ void async_ld16(const bf16* g, bf16* l) {
  __builtin_amdgcn_global_load_lds(
      (__attribute__((address_space(1))) void*)(void*)g,
      (__attribute__((address_space(3))) void*)(void*)l, 16, 0, 0);
}

template <int N>
__device__ __forceinline__ void vm_wait() {
  asm volatile("s_waitcnt vmcnt(%0)" ::"n"(N) : "memory");
}
__device__ __forceinline__ void lgkm0() {
  asm volatile("s_waitcnt lgkmcnt(0)" ::: "memory");
}
__device__ __forceinline__ void bar() {
  asm volatile("s_barrier" ::: "memory");
}
#define PIN() __builtin_amdgcn_sched_barrier(0)

// ---------------------------------------------------------------------------
// 256x256-tile bf16 GEMM, 3-barriers-per-K-tile (R8 core, FROZEN: best of 7
// schedule variants). C = A[M,K] @ B^T[N,K], fp32 accum via
// v_mfma_f32_16x16x32_bf16. 512 threads = 8 waves (2M x 4N), 128x64 C/wave.
//
// R13: LN fusion with OUT-OF-BAND stats. R12 proved the fused-LN algebra
// (absmax ok) but in-epilogue stats (shfl+atomic, 8-block contention) cost
// +51us/dispatch (WRITE_SIZE 49->98MB). Stats now come from a dedicated
// read-only kernel; the GEMM epilogue only CONSUMES them (per-row affine):
//   MODE 1: y = addb + relu( rstd*(acc - mu*sgW[n]) + bWbr[n] ),
//   mu/rstd from stats_in[m] = (sum y, sum y^2) of the A-row.
// WrT is g-folded at transpose time; sgW/bWbr precomputed (lnfold_kernel).
// Deletes the 9 LN round-trips (128MB each) and xnb; adds 9 stats passes
// (64MB read each).
//
// Sync structure (verified R7): 3 barriers/tile — barA / barB(vm_wait<8>) /
// barC as commented in the loop.
//
// LDS per matrix: [2 bufs][2 units][128 rows][64 cols] bf16, 128 KiB total.
// Unit u holds global rows (lr>>6)*128 + u*64 + (lr&63). Chunk swizzle:
// logical chunk cc of row r at slot cc^(r&7); global source pre-swizzled.
// Block mapping: n-major (bid%nbx) -> A panels L2-resident.
// C-column mapping: n = (wn>>1)*128 + NQ*64 + (wn&1)*32 + j*16 + l15
//
// MODE 0: C_bf16 = acc + bias[n]; optional split-output (fused K/V)
// MODE 1: fused-LN ResNet step (see above), in-place
// MODE 2: C_bf16[m&(NE-1), hidx*coloff+n] = acc+bias[n]+addb[m,n] (-> cat)
// MODE 3: C_f32[m,n] += acc                               (final += Q-K)

#define LDA_H(KS, BUF, MQ)                                                    \
  {                                                                           \
    const int ab_ = ((BUF)*2 + (MQ)) * 8192 + aOff;                           \
    const int co_ = (c0 ^ ((KS) << 2)) * 8;                                   \
    _Pragma("unroll") for (int i = 0; i < 4; ++i)                             \
        fa[KS][i] = *(const bf16x8*)&lA[ab_ + i * 1024 + co_];                \
  }

#define LDB_H(DST, KS, BUF, NQ)                                               \
  {                                                                           \
    const int bb_ = ((BUF)*2 + (NQ)) * 8192 + bOff;                           \
    const int co_ = (c0 ^ ((KS) << 2)) * 8;                                   \
    _Pragma("unroll") for (int j = 0; j < 2; ++j)                             \
        DST[KS][j] = *(const bf16x8*)&lB[bb_ + j * 1024 + co_];               \
  }

#define MFMA_H(KS, MQ, NQ, FB)                                                \
  __builtin_amdgcn_s_setprio(1);                                              \
  _Pragma("unroll") for (int i = 0; i < 4; ++i)                               \
  _Pragma("unroll") for (int j = 0; j < 2; ++j)                               \
      acc[(MQ)*4 + i][(NQ)*2 + j] = __builtin_amdgcn_mfma_f32_16x16x32_bf16(  \
          fa[KS][i], FB[KS][j], acc[(MQ)*4 + i][(NQ)*2 + j], 0, 0, 0);        \
  __builtin_amdgcn_s_setprio(0);

template <int MODE>
__global__ __launch_bounds__(512, 2) void gemm_kernel(
    const bf16* __restrict__ A, const bf16* __restrict__ B,
    const float* __restrict__ bias, void* __restrict__ Cv,
    const bf16* __restrict__ addb, int K, int ldc, int coloff, int addld,
    int nbx, int hsh, long long bstr, int bistr,
    const float* __restrict__ lnbb, const float* __restrict__ stats_in) {
  __shared__ bf16 lA[32768];  // [buf][unit][128][64]
  __shared__ bf16 lB[32768];

  // T1: XCD-aware block swizzle (all grids here are multiples of 8)
  const int nwg = gridDim.x;
  int bid = blockIdx.x;
  if ((nwg & 7) == 0) bid = (bid & 7) * (nwg >> 3) + (bid >> 3);
  const int n0 = (bid % nbx) * 256;
  const int m0 = (bid / nbx) * 256;

  // head-batched addressing (used only by the Wms launch)
  const int hidx = hsh ? (m0 >> hsh) : 0;
  if (hsh) {
    B += (size_t)hidx * (size_t)bstr;
    bias += (size_t)hidx * (size_t)bistr;
  }

  const int tid = threadIdx.x;
  const int wv = tid >> 6, ln = tid & 63;
  const int wm = wv >> 2, wn = wv & 3;  // 2x4 waves, each 128x64 of C

  // staging lane geometry: lane covers row (wv*8 + ln>>3), slot (ln&7),
  // fetching logical chunk (ln&7)^(ln>>3)  [pre-swizzled source]
  const int rowq = wv * 8 + (ln >> 3);
  const int colo = ((ln & 7) ^ (ln >> 3)) * 8;
  const bf16* gA = A + (size_t)(m0 + rowq) * K + colo;
  const bf16* gB = B + (size_t)(n0 + rowq) * K + colo;

  auto stageA = [&](int bf, int u, int t) {
#pragma unroll
    for (int r = 0; r < 2; ++r)
      async_ld16(gA + (size_t)(r * 128 + u * 64) * K + t * 64,
                 &lA[((bf * 2 + u) * 128 + r * 64 + wv * 8) * 64]);
  };
  auto stageB = [&](int bf, int u, int t) {
#pragma unroll
    for (int r = 0; r < 2; ++r)
      async_ld16(gB + (size_t)(r * 128 + u * 64) * K + t * 64,
                 &lB[((bf * 2 + u) * 128 + r * 64 + wv * 8) * 64]);
  };

  // fragment read geometry (16x16x32: A row = ln&15, k-chunk = ln>>4)
  const int l15 = ln & 15;
  const int aOff = (wm * 64 + l15) * 64;  // unit-local row * 64
  const int bOff = (wn * 32 + l15) * 64;
  const int c0 = (ln >> 4) ^ (ln & 7);    // swizzled chunk slot, ks=0

  f32x4 acc[8][4] = {};
  bf16x8 fa[2][4], fb0[2][2], fb1[2][2];

  const int nt = K >> 6;

  // prologue: stage tiles 0 and 1 fully; vm_wait<8> retires tile 0 (leaves
  // tile 1's 8 in flight); prefetch F(0)'s leading frags (fa-MQ0, fb0);
  // lgkm0+bar so tile0's unit[0] staging is >=1 bar after these reads.
  stageA(0, 0, 0); stageA(0, 1, 0); stageB(0, 0, 0); stageB(0, 1, 0);
  stageA(1, 0, 1); stageA(1, 1, 1); stageB(1, 0, 1); stageB(1, 1, 1);
  vm_wait<8>();
  bar();
  LDA_H(0, 0, 0); LDA_H(1, 0, 0); LDB_H(fb0, 0, 0, 0); LDB_H(fb0, 1, 0, 0);
  lgkm0();
  bar();

  for (int t = 0; t < nt; ++t) {
    const int buf = t & 1, nb = buf ^ 1;
    const bool s1 = t + 1 < nt, s2 = t + 2 < nt;
    // ---- Half1: quadrants (0,0),(0,1) ----
    if (s2) { stageB(buf, 0, t + 2); stageA(buf, 0, t + 2); }
    PIN();
    LDB_H(fb1, 0, buf, 1); LDB_H(fb1, 1, buf, 1);
    PIN();
    MFMA_H(0, 0, 0, fb0);
    MFMA_H(1, 0, 0, fb0);
    MFMA_H(0, 0, 1, fb1);
    PIN();
    LDA_H(0, buf, 1);            // fa[0] <- MQ1-ks0 (MQ0-ks0 dead)
    PIN();
    MFMA_H(1, 0, 1, fb1);
    PIN();
    LDA_H(1, buf, 1);            // fa[1] <- MQ1-ks1
    lgkm0();
    bar();                        // barA
    // ---- Half2a: quadrant (1,1); stage units[1]; retire t+1 ----
    if (s2) { stageB(buf, 1, t + 2); stageA(buf, 1, t + 2); }
    PIN();
    MFMA_H(0, 1, 1, fb1);
    MFMA_H(1, 1, 1, fb1);
    if (s2) { vm_wait<8>(); } else if (s1) { vm_wait<0>(); }
    bar();                        // barB (publishes tile t+1)
    // ---- Half2b: quadrant (1,0); prefetch F(t+1) leading frags ----
    MFMA_H(0, 1, 0, fb0);
    PIN();
    if (s1) { LDB_H(fb0, 0, nb, 0); LDA_H(0, nb, 0); }
    PIN();
    MFMA_H(1, 1, 0, fb0);
    PIN();
    if (s1) { LDB_H(fb0, 1, nb, 0); LDA_H(1, nb, 0); }
    lgkm0();
    bar();                        // barC
  }

  // epilogue: 16x16 C/D layout col = ln&15, row = (ln>>4)*4 + r.
  const int r4 = (ln >> 4) * 4;
  const int nbase = n0 + (wn >> 1) * 128 + (wn & 1) * 32 + l15;
#pragma unroll
  for (int mi = 0; mi < 8; ++mi) {
#pragma unroll
    for (int r = 0; r < 4; ++r) {
      const int m = m0 + wm * 128 + mi * 16 + r4 + r;
      float mu = 0.f, rstd = 0.f;
      if constexpr (MODE == 1) {
        const float2 st = *(const float2*)&stats_in[2 * m];
        mu = st.x * (1.f / NM);
        const float var = st.y * (1.f / NM) - mu * mu;
        rstd = rsqrtf(fmaxf(var, 0.f) + 1e-5f);
      }
#pragma unroll
      for (int ni = 0; ni < 4; ++ni) {
        const int n = nbase + (ni >> 1) * 64 + (ni & 1) * 16;
        float v = acc[mi][ni][r];
        if constexpr (MODE == 0) {
          v += bias[n];
          size_t idx = (size_t)m * ldc + n;
          if (coloff && n >= coloff) idx += (size_t)addld;  // split output
          ((bf16*)Cv)[idx] = (bf16)v;
        } else if constexpr (MODE == 1) {
          v = rstd * (v - mu * bias[n]) + lnbb[n];  // bias == sgW here
          const float prev = (float)addb[(size_t)m * addld + n];
          ((bf16*)Cv)[(size_t)m * ldc + n] = (bf16)(prev + fmaxf(v, 0.f));
        } else if constexpr (MODE == 2) {
          v += bias[n];
          v += (float)addb[(size_t)m * addld + n];
          const int mloc = hsh ? (m & ((1 << hsh) - 1)) : m;
          ((bf16*)Cv)[(size_t)mloc * ldc + hidx * coloff + n] = (bf16)v;
        } else {
          float* C = (float*)Cv;
          const size_t idx = (size_t)m * ldc + n;
          C[idx] = C[idx] + v;
        }
      }
    }
  }
}

template <int MODE>
static void launch_gemm(hipStream_t s, const bf16* A, const bf16* B,
                        const float* bias, void* C, const bf16* addb, int M,
                        int N, int K, int ldc, int coloff, int addld,
                        int hsh = 0, long long bstr = 0, int bistr = 0,
                        const float* lnbb = nullptr,
                        const float* stats_in = nullptr) {
  const int nbx = N / 256;
  gemm_kernel<MODE><<<dim3(nbx * (M / 256)), 512, 0, s>>>(
      A, B, bias, C, addb, K, ldc, coloff, addld, nbx, hsh, bstr, bistr,
      lnbb, stats_in);
}

// ---------------------------------------------------------------------------
// stats[e] = (sum_k x[e][k], sum_k x[e][k]^2) over rows of 2048 (read-only)
__global__ __launch_bounds__(256) void stats_kernel(
    const bf16* __restrict__ x, float* __restrict__ stats) {
  __shared__ float sm[8];
  const int tid = threadIdx.x;
  const size_t base = (size_t)blockIdx.x * NM + tid * 8;
  const bf16x8 xv = *(const bf16x8*)(x + base);
  float s = 0.f, ss = 0.f;
#pragma unroll
  for (int i = 0; i < 8; ++i) {
    const float f = (float)xv[i];
    s += f;
    ss += f * f;
  }
#pragma unroll
  for (int o = 32; o > 0; o >>= 1) {
    s += __shfl_down(s, o, 64);
    ss += __shfl_down(ss, o, 64);
  }
  if ((tid & 63) == 0) {
    sm[tid >> 6] = s;
    sm[4 + (tid >> 6)] = ss;
  }
  __syncthreads();
  if (tid == 0) {
    float2 st;
    st.x = sm[0] + sm[1] + sm[2] + sm[3];
    st.y = sm[4] + sm[5] + sm[6] + sm[7];
    *(float2*)&stats[2 * blockIdx.x] = st;
  }
}

// ---------------------------------------------------------------------------
// fp32 [K,N] -> bf16 [N,K] transpose-convert, 32x32 tiles, batched over z.
// Optional per-k scale (scale[z*K + k]) for LN g-folding into WrT.
__global__ void transpose_cvt(const float* __restrict__ src,
                              bf16* __restrict__ dst, int K, int N,
                              const float* __restrict__ scale) {
  __shared__ float t[32][33];
  const int z = blockIdx.z;
  const size_t zo = (size_t)z * K * N;
  src += zo;
  dst += zo;
  const int n = blockIdx.x * 32 + threadIdx.x;
  const int kb = blockIdx.y * 32;
#pragma unroll
  for (int i = 0; i < 4; ++i) {
    const int k = kb + threadIdx.y + i * 8;
    t[threadIdx.y + i * 8][threadIdx.x] = src[(size_t)k * N + n];
  }
  __syncthreads();
  const float sc = scale ? scale[(size_t)z * K + kb + threadIdx.x] : 1.f;
#pragma unroll
  for (int i = 0; i < 4; ++i) {
    const int nn = blockIdx.x * 32 + threadIdx.y + i * 8;
    dst[(size_t)nn * K + kb + threadIdx.x] =
        (bf16)(t[threadIdx.x][threadIdx.y + i * 8] * sc);
  }
}

// ---------------------------------------------------------------------------
// sgW[hj][n] = sum_k g[hj][k]*Wr[hj][k][n]; bWbr[hj][n] = sum_k b*Wr + br[n]
__global__ void lnfold_kernel(const float* __restrict__ Wr,
                              const float* __restrict__ g,
                              const float* __restrict__ b,
                              const float* __restrict__ br,
                              float* __restrict__ sgW,
                              float* __restrict__ bWbr) {
  const int hj = blockIdx.y;
  const int n = blockIdx.x * 256 + threadIdx.x;
  const float* W = Wr + (size_t)hj * NM * NM;
  float sg = 0.f, sb = 0.f;
  for (int k = 0; k < NM; ++k) {
    const float w = W[(size_t)k * NM + n];
    sg += g[hj * NM + k] * w;
    sb += b[hj * NM + k] * w;
  }
  sgW[hj * NM + n] = sg;
  bWbr[hj * NM + n] = sb + br[hj * NM + n];
}

// ---------------------------------------------------------------------------
// concat two fp32 vectors (bk|bv) -> dst
__global__ void concat2_kernel(const float* __restrict__ a,
                               const float* __restrict__ b,
                               float* __restrict__ dst, int na) {
  const int i = blockIdx.x * 256 + threadIdx.x;
  dst[i] = (i < na) ? a[i] : b[i - na];
}

// ---------------------------------------------------------------------------
// Q = normalize(h)[src], K = rep[dst]; emit bf16 Q,K and fp32 (Q-K) -> d_out
__global__ __launch_bounds__(256) void gather_kernel(
    const float* __restrict__ h, const float* __restrict__ rep,
    const int* __restrict__ src, const int* __restrict__ dst,
    bf16* __restrict__ Qb, bf16* __restrict__ Kb, float* __restrict__ qk) {
  __shared__ float sm[4];
  const int e = blockIdx.x, tid = threadIdx.x;
  const int sr = src[e], dr = dst[e];
  const float4 hv = ((const float4*)(h + (size_t)sr * ND))[tid];
  float ss = hv.x * hv.x + hv.y * hv.y + hv.z * hv.z + hv.w * hv.w;
#pragma unroll
  for (int o = 32; o > 0; o >>= 1) ss += __shfl_down(ss, o, 64);
  if ((tid & 63) == 0) sm[tid >> 6] = ss;
  __syncthreads();
  const float tot = sm[0] + sm[1] + sm[2] + sm[3];
  const float inv = 1.f / fmaxf(sqrtf(tot), 1e-12f);
  const float4 rv = ((const float4*)(rep + (size_t)dr * ND))[tid];
  const float q0 = hv.x * inv, q1 = hv.y * inv, q2 = hv.z * inv,
              q3 = hv.w * inv;
  const size_t base = (size_t)e * ND + tid * 4;
  bf16x4 qv;
  qv[0] = (bf16)q0; qv[1] = (bf16)q1; qv[2] = (bf16)q2; qv[3] = (bf16)q3;
  *(bf16x4*)(Qb + base) = qv;
  bf16x4 kv;
  kv[0] = (bf16)rv.x; kv[1] = (bf16)rv.y; kv[2] = (bf16)rv.z;
  kv[3] = (bf16)rv.w;
  *(bf16x4*)(Kb + base) = kv;
  *(float4*)(qk + base) =
      make_float4(q0 - rv.x, q1 - rv.y, q2 - rv.z, q3 - rv.w);
}

// ---------------------------------------------------------------------------
// attn = softmax(Qp*Kp/sqrt(A), axis=-1) * Vp   (per row of 512)
// Qp/Kp/Vp are [E][H*A]; attn out is [h][E][A]. grid = (E, H).
__global__ __launch_bounds__(256) void softmax_kernel(
    const bf16* __restrict__ Qp, const bf16* __restrict__ Kp,
    const bf16* __restrict__ Vp, bf16* __restrict__ attn) {
  __shared__ float sm[4];
  const int tid = threadIdx.x;
  const int e = blockIdx.x, hh = blockIdx.y;
  const size_t base = (size_t)e * (NH * NA) + (size_t)hh * NA + 2 * tid;
  const bf16x2 q = *(const bf16x2*)(Qp + base);
  const bf16x2 k = *(const bf16x2*)(Kp + base);
  const bf16x2 v = *(const bf16x2*)(Vp + base);
  const float sc = 0.044194173824159216f;  // 1/sqrt(512)
  const float s0 = (float)q[0] * (float)k[0] * sc;
  const float s1 = (float)q[1] * (float)k[1] * sc;
  float mx = fmaxf(s0, s1);
#pragma unroll
  for (int o = 32; o > 0; o >>= 1) mx = fmaxf(mx, __shfl_down(mx, o, 64));
  if ((tid & 63) == 0) sm[tid >> 6] = mx;
  __syncthreads();
  mx = fmaxf(fmaxf(sm[0], sm[1]), fmaxf(sm[2], sm[3]));
  __syncthreads();
  const float p0 = expf(s0 - mx), p1 = expf(s1 - mx);
  float ssum = p0 + p1;
#pragma unroll
  for (int o = 32; o > 0; o >>= 1) ssum += __shfl_down(ssum, o, 64);
  if ((tid & 63) == 0) sm[tid >> 6] = ssum;
  __syncthreads();
  const float inv = 1.f / (sm[0] + sm[1] + sm[2] + sm[3]);
  bf16x2 r;
  r[0] = (bf16)(p0 * inv * (float)v[0]);
  r[1] = (bf16)(p1 * inv * (float)v[1]);
  const size_t obase = (size_t)hh * NE * NA + (size_t)e * NA + 2 * tid;
  *(bf16x2*)(attn + obase) = r;
}

// ---------------------------------------------------------------------------
extern "C" void kernel_launch(void* const* d_in, const int* in_sizes, int n_in,
                              void* d_out, int out_size, void* d_ws,
                              size_t ws_size, hipStream_t stream) {
  const float* h    = (const float*)d_in[0];
  const float* rep  = (const float*)d_in[1];
  const int* src    = (const int*)d_in[2];
  const int* dst    = (const int*)d_in[3];
  const float* Wq   = (const float*)d_in[4];
  const float* bq   = (const float*)d_in[5];
  const float* Wk   = (const float*)d_in[6];
  const float* bk   = (const float*)d_in[7];
  const float* Wv   = (const float*)d_in[8];
  const float* bv   = (const float*)d_in[9];
  const float* W0   = (const float*)d_in[10];
  const float* b0   = (const float*)d_in[11];
  const float* Wr   = (const float*)d_in[12];
  const float* br   = (const float*)d_in[13];
  const float* g_ln = (const float*)d_in[14];
  const float* b_ln = (const float*)d_in[15];
  const float* Wms  = (const float*)d_in[16];
  const float* bms  = (const float*)d_in[17];
  const float* Wuas = (const float*)d_in[18];
  float* out = (float*)d_out;

  bf16* ws = (bf16*)d_ws;
  size_t off = 0;
  auto alloc = [&](size_t n) {
    bf16* p = ws + off;
    off += n;
    return p;
  };
  bf16* WqT   = alloc((size_t)NH * NA * ND);       // [h*512][1024]
  bf16* WkT   = alloc((size_t)NH * NA * ND);       // contiguous with WvT!
  bf16* WvT   = alloc((size_t)NH * NA * ND);
  bf16* W0T   = alloc((size_t)NH * NM * NA);       // [h][2048][512]
  bf16* WrT   = alloc((size_t)NH * NRES * NM * NM);// [h*3+j][2048][2048] g-folded
  bf16* WmsT  = alloc((size_t)NH * NA * NM);       // [h][512][2048]
  bf16* WuasT = alloc((size_t)ND * NH * NA);       // [1024][1536]
  bf16* Qb    = alloc((size_t)NE * ND);
  bf16* Kb    = alloc((size_t)NE * ND);
  bf16* Qp    = alloc((size_t)NE * NH * NA);       // [E][1536]; reused as cat
  bf16* Kp    = alloc((size_t)NE * NH * NA);       // Kp then Vp contiguous
  bf16* Vp    = alloc((size_t)NE * NH * NA);
  bf16* attn  = alloc((size_t)NH * NE * NA);       // [h][E][512]
  bf16* mbuf3 = alloc((size_t)NH * NE * NM);       // [h][E][2048] (persists)
  float* cbias = (float*)alloc(2 * (size_t)NH * NA * 2);      // fp32[3072]
  float* sgW   = (float*)alloc((size_t)NH * NRES * NM * 2);   // fp32[9][2048]
  float* bWbr  = (float*)alloc((size_t)NH * NRES * NM * 2);   // fp32[9][2048]
  float* stats = (float*)alloc((size_t)NE * 2 * 2);           // fp32[NE][2]
  bf16* cat   = Qp;                                // alias: Qp dead after softmax
  if (ws_size < off * sizeof(bf16)) return;  // workspace too small: bail

  const dim3 tb(32, 8);
  transpose_cvt<<<dim3(NA / 32, ND / 32, NH), tb, 0, stream>>>(Wq, WqT, ND, NA,
                                                               nullptr);
  transpose_cvt<<<dim3(NA / 32, ND / 32, NH), tb, 0, stream>>>(Wk, WkT, ND, NA,
                                                               nullptr);
  transpose_cvt<<<dim3(NA / 32, ND / 32, NH), tb, 0, stream>>>(Wv, WvT, ND, NA,
                                                               nullptr);
  transpose_cvt<<<dim3(NM / 32, NA / 32, NH), tb, 0, stream>>>(W0, W0T, NA, NM,
                                                               nullptr);
  // WrT with LN gamma folded in: WrT[n][k] = Wr[k][n] * g_ln[k]
  transpose_cvt<<<dim3(NM / 32, NM / 32, NH * NRES), tb, 0, stream>>>(
      Wr, WrT, NM, NM, g_ln);
  transpose_cvt<<<dim3(NA / 32, NM / 32, NH), tb, 0, stream>>>(Wms, WmsT, NM,
                                                               NA, nullptr);
  transpose_cvt<<<dim3(ND / 32, (NH * NA) / 32, 1), tb, 0, stream>>>(
      Wuas, WuasT, NH * NA, ND, nullptr);
  concat2_kernel<<<(2 * NH * NA) / 256, 256, 0, stream>>>(bk, bv, cbias,
                                                          NH * NA);
  lnfold_kernel<<<dim3(NM / 256, NH * NRES), 256, 0, stream>>>(
      Wr, g_ln, b_ln, br, sgW, bWbr);

  gather_kernel<<<NE, 256, 0, stream>>>(h, rep, src, dst, Qb, Kb, out);

  // Q projection: N = H*A = 1536
  launch_gemm<0>(stream, Qb, WqT, bq, Qp, nullptr, NE, NH * NA, ND, NH * NA,
                 0, 0);
  // fused K+V projection: N = 3072 (B = [WkT;WvT] contiguous), split output:
  // n<1536 -> Kp[m*1536+n], n>=1536 -> Vp[m*1536+n-1536] = +(NE-1)*1536
  launch_gemm<0>(stream, Kb, WkT, cbias, Kp, nullptr, NE, 2 * NH * NA, ND,
                 NH * NA, NH * NA, (NE - 1) * NH * NA);
  softmax_kernel<<<dim3(NE, NH), 256, 0, stream>>>(Qp, Kp, Vp, attn);

  // per-head MLP chain; LN fused into ResNet GEMM, stats out-of-band
  for (int hh = 0; hh < NH; ++hh) {
    const bf16* attn_h = attn + (size_t)hh * NE * NA;
    bf16* mbuf_h = mbuf3 + (size_t)hh * NE * NM;
    launch_gemm<0>(stream, attn_h, W0T + (size_t)hh * NM * NA, b0 + hh * NM,
                   mbuf_h, nullptr, NE, NM, NA, NM, 0, 0);
    for (int j = 0; j < NRES; ++j) {
      const int hj = hh * NRES + j;
      stats_kernel<<<NE, 256, 0, stream>>>(mbuf_h, stats);
      launch_gemm<1>(stream, mbuf_h, WrT + (size_t)hj * NM * NM,
                     sgW + (size_t)hj * NM, mbuf_h, mbuf_h, NE, NM, NM, NM, 0,
                     NM, 0, 0, 0, bWbr + (size_t)hj * NM, stats);
    }
  }
  // head-batched Wms: M = 3E -> 384 blocks
  // cat[e][h*512+n] = mbuf3[h][e][:] @ WmsT[h] + bms[h] + attn[h][e][n]
  launch_gemm<2>(stream, mbuf3, WmsT, bms, cat, attn, NH * NE, NA, NM,
                 NH * NA, NA, NA, ESH, (long long)NA * NM, NA);

  launch_gemm<3>(stream, cat, WuasT, nullptr, out, nullptr, NE, ND, NH * NA,
                 ND, 0, 0);
}

// Round 14
// 2549.746 us; speedup vs baseline: 1.1608x; 1.0255x over previous
//
#include <hip/hip_runtime.h>
#include <hip/hip_bf16.h>
#include <cstdint>
#include <cstddef>

typedef __bf16 bf16;
typedef __bf16 bf16x2 __attribute__((ext_vector_type(2)));
typedef __bf16 bf16x4 __attribute__((ext_vector_type(4)));
typedef __bf16 bf16x8 __attribute__((ext_vector_type(8)));
typedef float f32x4 __attribute__((ext_vector_type(4)));

static_assert(sizeof(bf16x8) == 16, "bf16x8 must be 16B");

#define NE 16384   // E
#define ND 1024    // D
#define NA 512     // A
#define NM 2048    // M
#define NH 3
#define NRES 3
#define ESH 14     // log2(NE)

// ---------------------------------------------------------------------------
// async global->LDS, 16B per lane (wave-uniform LDS base + lane*16 implicit)
__device__ __forceinline__ void async_ld16(const bf16* g, bf16* l) {
  __builtin_amdgcn_global_load_lds(
      (__attribute__((address_space(1))) void*)(void*)g,
      (__attribute__((address_space(3))) void*)(void*)l, 16, 0, 0);
}

template <int N>
__device__ __forceinline__ void vm_wait() {
  asm volatile("s_waitcnt vmcnt(%0)" ::"n"(N) : "memory");
}
__device__ __forceinline__ void lgkm0() {
  asm volatile("s_waitcnt lgkmcnt(0)" ::: "memory");
}
__device__ __forceinline__ void bar() {
  asm volatile("s_barrier" ::: "memory");
}

// ---------------------------------------------------------------------------
// R14 GEMM core: m97-class 128x128 tile, BK=64, 256 threads = 4 waves (2x2,
// 64x64 C each), SINGLE-buffered 32 KiB LDS -> ~3 blocks/CU. Rationale: all
// seven 256^2 single-block-per-CU schedule variants pinned at 28-35% MfmaUtil
// (whole-CU barrier stalls); m97/m103 [measured 874-912 TF] recover those
// stalls via CROSS-BLOCK overlap (m114), not in-block scheduling.
// K-loop per 64-wide tile:
//   vm_wait(0)+bar   -> tile t resident (stage issued last iter, overlapped)
//   16 ds_read_b128  -> fa[2][4], fb[2][4]
//   lgkm0 + bar      -> all waves' reads drained; LDS free
//   stage(t+1)       -> 8 global_load_lds (overlaps the MFMAs below)
//   32 MFMA (setprio-wrapped)
// Chunk swizzle (unchanged, verified): logical chunk cc of row r at slot
// cc^(r&7); global source pre-swizzled; row&7 == ln>>3 for every stage issue.
// Block mapping: n-major (bid%nbx) -> A panels L2-resident + XCD swizzle.
// C mapping: m = m0 + wm*64 + mi*16 + (ln>>4)*4 + r;
//            n = n0 + wn*64 + ni*16 + (ln&15)   (direct, 2x2 waves)
//
// MODE 0: C_bf16 = acc + bias[n]; optional split-output (fused K/V)
// MODE 1: C_bf16 = addb[m,n] + relu(acc + bias[n])        (residual, in-place)
// MODE 2: C_bf16[m&(NE-1), hidx*coloff+n] = acc+bias[n]+addb[m,n] (-> cat)
// MODE 3: C_f32[m,n] += acc                               (final += Q-K)

template <int MODE>
__global__ __launch_bounds__(256, 3) void gemm_kernel(
    const bf16* __restrict__ A, const bf16* __restrict__ B,
    const float* __restrict__ bias, void* __restrict__ Cv,
    const bf16* __restrict__ addb, int K, int ldc, int coloff, int addld,
    int nbx, int hsh, long long bstr, int bistr) {
  __shared__ bf16 lA[8192];  // [128][64]
  __shared__ bf16 lB[8192];

  // T1: XCD-aware block swizzle (all grids here are multiples of 8)
  const int nwg = gridDim.x;
  int bid = blockIdx.x;
  if ((nwg & 7) == 0) bid = (bid & 7) * (nwg >> 3) + (bid >> 3);
  const int n0 = (bid % nbx) * 128;
  const int m0 = (bid / nbx) * 128;

  // head-batched addressing (used only by the Wms launch)
  const int hidx = hsh ? (m0 >> hsh) : 0;
  if (hsh) {
    B += (size_t)hidx * (size_t)bstr;
    bias += (size_t)hidx * (size_t)bistr;
  }

  const int tid = threadIdx.x;
  const int wv = tid >> 6, ln = tid & 63;
  const int wm = wv >> 1, wn = wv & 1;  // 2x2 waves, each 64x64 of C

  // staging lane geometry: wave wv covers rows r*32 + wv*8 + (ln>>3); slot
  // ln&7 fetches logical chunk (ln&7)^(ln>>3) [pre-swizzled source; row&7 is
  // ln>>3 for every issue since r*32, wv*8 are 0 mod 8]
  const int rowq = wv * 8 + (ln >> 3);
  const int colo = ((ln & 7) ^ (ln >> 3)) * 8;
  const bf16* gA = A + (size_t)(m0 + rowq) * K + colo;
  const bf16* gB = B + (size_t)(n0 + rowq) * K + colo;

  auto stage = [&](int t) {
#pragma unroll
    for (int r = 0; r < 4; ++r) {
      async_ld16(gA + (size_t)(r * 32) * K + t * 64,
                 &lA[(r * 32 + wv * 8) * 64]);
      async_ld16(gB + (size_t)(r * 32) * K + t * 64,
                 &lB[(r * 32 + wv * 8) * 64]);
    }
  };

  // fragment read geometry (16x16x32: row = base + l15, k-chunk = ln>>4)
  const int l15 = ln & 15;
  const int aOff = (wm * 64 + l15) * 64;
  const int bOff = (wn * 64 + l15) * 64;
  const int c0 = (ln >> 4) ^ (ln & 7);  // swizzled chunk slot, ks=0

  f32x4 acc[4][4] = {};
  bf16x8 fa[2][4], fb[2][4];

  const int nt = K >> 6;

  stage(0);

  for (int t = 0; t < nt; ++t) {
    vm_wait<0>();
    bar();                       // tile t resident + published
#pragma unroll
    for (int ks = 0; ks < 2; ++ks) {
      const int co = (c0 ^ (ks << 2)) * 8;
#pragma unroll
      for (int i = 0; i < 4; ++i)
        fa[ks][i] = *(const bf16x8*)&lA[aOff + i * 1024 + co];
#pragma unroll
      for (int j = 0; j < 4; ++j)
        fb[ks][j] = *(const bf16x8*)&lB[bOff + j * 1024 + co];
    }
    lgkm0();
    bar();                       // all waves' reads drained; LDS free
    if (t + 1 < nt) stage(t + 1);  // async, overlaps the MFMAs below
    __builtin_amdgcn_s_setprio(1);
#pragma unroll
    for (int ks = 0; ks < 2; ++ks)
#pragma unroll
      for (int i = 0; i < 4; ++i)
#pragma unroll
        for (int j = 0; j < 4; ++j)
          acc[i][j] = __builtin_amdgcn_mfma_f32_16x16x32_bf16(
              fa[ks][i], fb[ks][j], acc[i][j], 0, 0, 0);
    __builtin_amdgcn_s_setprio(0);
  }

  // epilogue: 16x16 C/D layout col = ln&15, row = (ln>>4)*4 + r
  const int r4 = (ln >> 4) * 4;
  const int nbase = n0 + wn * 64 + l15;
#pragma unroll
  for (int mi = 0; mi < 4; ++mi) {
#pragma unroll
    for (int r = 0; r < 4; ++r) {
      const int m = m0 + wm * 64 + mi * 16 + r4 + r;
#pragma unroll
      for (int ni = 0; ni < 4; ++ni) {
        const int n = nbase + ni * 16;
        float v = acc[mi][ni][r];
        if constexpr (MODE != 3) v += bias[n];
        if constexpr (MODE == 0) {
          size_t idx = (size_t)m * ldc + n;
          if (coloff && n >= coloff) idx += (size_t)addld;  // split output
          ((bf16*)Cv)[idx] = (bf16)v;
        } else if constexpr (MODE == 1) {
          float prev = (float)addb[(size_t)m * addld + n];
          ((bf16*)Cv)[(size_t)m * ldc + n] = (bf16)(prev + fmaxf(v, 0.f));
        } else if constexpr (MODE == 2) {
          v += (float)addb[(size_t)m * addld + n];
          const int mloc = hsh ? (m & ((1 << hsh) - 1)) : m;
          ((bf16*)Cv)[(size_t)mloc * ldc + hidx * coloff + n] = (bf16)v;
        } else {
          float* C = (float*)Cv;
          const size_t idx = (size_t)m * ldc + n;
          C[idx] = C[idx] + v;
        }
      }
    }
  }
}

template <int MODE>
static void launch_gemm(hipStream_t s, const bf16* A, const bf16* B,
                        const float* bias, void* C, const bf16* addb, int M,
                        int N, int K, int ldc, int coloff, int addld,
                        int hsh = 0, long long bstr = 0, int bistr = 0) {
  const int nbx = N / 128;
  gemm_kernel<MODE><<<dim3(nbx * (M / 128)), 256, 0, s>>>(
      A, B, bias, C, addb, K, ldc, coloff, addld, nbx, hsh, bstr, bistr);
}

// ---------------------------------------------------------------------------
// fp32 [K,N] -> bf16 [N,K] transpose-convert, 32x32 tiles, batched over z
__global__ void transpose_cvt(const float* __restrict__ src,
                              bf16* __restrict__ dst, int K, int N) {
  __shared__ float t[32][33];
  const size_t zo = (size_t)blockIdx.z * K * N;
  src += zo;
  dst += zo;
  const int n = blockIdx.x * 32 + threadIdx.x;
  const int kb = blockIdx.y * 32;
#pragma unroll
  for (int i = 0; i < 4; ++i) {
    const int k = kb + threadIdx.y + i * 8;
    t[threadIdx.y + i * 8][threadIdx.x] = src[(size_t)k * N + n];
  }
  __syncthreads();
#pragma unroll
  for (int i = 0; i < 4; ++i) {
    const int nn = blockIdx.x * 32 + threadIdx.y + i * 8;
    dst[(size_t)nn * K + kb + threadIdx.x] =
        (bf16)t[threadIdx.x][threadIdx.y + i * 8];
  }
}

// ---------------------------------------------------------------------------
// concat two fp32 vectors (bk|bv) -> dst
__global__ void concat2_kernel(const float* __restrict__ a,
                               const float* __restrict__ b,
                               float* __restrict__ dst, int na) {
  const int i = blockIdx.x * 256 + threadIdx.x;
  dst[i] = (i < na) ? a[i] : b[i - na];
}

// ---------------------------------------------------------------------------
// Q = normalize(h)[src], K = rep[dst]; emit bf16 Q,K and fp32 (Q-K) -> d_out
__global__ __launch_bounds__(256) void gather_kernel(
    const float* __restrict__ h, const float* __restrict__ rep,
    const int* __restrict__ src, const int* __restrict__ dst,
    bf16* __restrict__ Qb, bf16* __restrict__ Kb, float* __restrict__ qk) {
  __shared__ float sm[4];
  const int e = blockIdx.x, tid = threadIdx.x;
  const int sr = src[e], dr = dst[e];
  const float4 hv = ((const float4*)(h + (size_t)sr * ND))[tid];
  float ss = hv.x * hv.x + hv.y * hv.y + hv.z * hv.z + hv.w * hv.w;
#pragma unroll
  for (int o = 32; o > 0; o >>= 1) ss += __shfl_down(ss, o, 64);
  if ((tid & 63) == 0) sm[tid >> 6] = ss;
  __syncthreads();
  const float tot = sm[0] + sm[1] + sm[2] + sm[3];
  const float inv = 1.f / fmaxf(sqrtf(tot), 1e-12f);
  const float4 rv = ((const float4*)(rep + (size_t)dr * ND))[tid];
  const float q0 = hv.x * inv, q1 = hv.y * inv, q2 = hv.z * inv,
              q3 = hv.w * inv;
  const size_t base = (size_t)e * ND + tid * 4;
  bf16x4 qv;
  qv[0] = (bf16)q0; qv[1] = (bf16)q1; qv[2] = (bf16)q2; qv[3] = (bf16)q3;
  *(bf16x4*)(Qb + base) = qv;
  bf16x4 kv;
  kv[0] = (bf16)rv.x; kv[1] = (bf16)rv.y; kv[2] = (bf16)rv.z;
  kv[3] = (bf16)rv.w;
  *(bf16x4*)(Kb + base) = kv;
  *(float4*)(qk + base) =
      make_float4(q0 - rv.x, q1 - rv.y, q2 - rv.z, q3 - rv.w);
}

// ---------------------------------------------------------------------------
// attn = softmax(Qp*Kp/sqrt(A), axis=-1) * Vp   (per row of 512)
// Qp/Kp/Vp are [E][H*A]; attn out is [h][E][A]. grid = (E, H).
__global__ __launch_bounds__(256) void softmax_kernel(
    const bf16* __restrict__ Qp, const bf16* __restrict__ Kp,
    const bf16* __restrict__ Vp, bf16* __restrict__ attn) {
  __shared__ float sm[4];
  const int tid = threadIdx.x;
  const int e = blockIdx.x, hh = blockIdx.y;
  const size_t base = (size_t)e * (NH * NA) + (size_t)hh * NA + 2 * tid;
  const bf16x2 q = *(const bf16x2*)(Qp + base);
  const bf16x2 k = *(const bf16x2*)(Kp + base);
  const bf16x2 v = *(const bf16x2*)(Vp + base);
  const float sc = 0.044194173824159216f;  // 1/sqrt(512)
  const float s0 = (float)q[0] * (float)k[0] * sc;
  const float s1 = (float)q[1] * (float)k[1] * sc;
  float mx = fmaxf(s0, s1);
#pragma unroll
  for (int o = 32; o > 0; o >>= 1) mx = fmaxf(mx, __shfl_down(mx, o, 64));
  if ((tid & 63) == 0) sm[tid >> 6] = mx;
  __syncthreads();
  mx = fmaxf(fmaxf(sm[0], sm[1]), fmaxf(sm[2], sm[3]));
  __syncthreads();
  const float p0 = expf(s0 - mx), p1 = expf(s1 - mx);
  float ssum = p0 + p1;
#pragma unroll
  for (int o = 32; o > 0; o >>= 1) ssum += __shfl_down(ssum, o, 64);
  if ((tid & 63) == 0) sm[tid >> 6] = ssum;
  __syncthreads();
  const float inv = 1.f / (sm[0] + sm[1] + sm[2] + sm[3]);
  bf16x2 r;
  r[0] = (bf16)(p0 * inv * (float)v[0]);
  r[1] = (bf16)(p1 * inv * (float)v[1]);
  const size_t obase = (size_t)hh * NE * NA + (size_t)e * NA + 2 * tid;
  *(bf16x2*)(attn + obase) = r;
}

// ---------------------------------------------------------------------------
// y = LN(x) * g + b over rows of 2048
__global__ __launch_bounds__(256) void ln_kernel(const bf16* __restrict__ x,
                                                 bf16* __restrict__ y,
                                                 const float* __restrict__ g,
                                                 const float* __restrict__ b) {
  __shared__ float sm[8];
  const int tid = threadIdx.x;
  const size_t base = (size_t)blockIdx.x * NM + tid * 8;
  const bf16x8 xv = *(const bf16x8*)(x + base);
  float xf[8], s = 0.f, ss = 0.f;
#pragma unroll
  for (int i = 0; i < 8; ++i) {
    xf[i] = (float)xv[i];
    s += xf[i];
    ss += xf[i] * xf[i];
  }
#pragma unroll
  for (int o = 32; o > 0; o >>= 1) {
    s += __shfl_down(s, o, 64);
    ss += __shfl_down(ss, o, 64);
  }
  if ((tid & 63) == 0) {
    sm[tid >> 6] = s;
    sm[4 + (tid >> 6)] = ss;
  }
  __syncthreads();
  s = sm[0] + sm[1] + sm[2] + sm[3];
  ss = sm[4] + sm[5] + sm[6] + sm[7];
  const float mu = s * (1.f / NM);
  const float var = ss * (1.f / NM) - mu * mu;
  const float rstd = rsqrtf(fmaxf(var, 0.f) + 1e-5f);
  const int c0 = tid * 8;
  bf16x8 yv;
#pragma unroll
  for (int i = 0; i < 8; ++i)
    yv[i] = (bf16)((xf[i] - mu) * rstd * g[c0 + i] + b[c0 + i]);
  *(bf16x8*)(y + base) = yv;
}

// ---------------------------------------------------------------------------
extern "C" void kernel_launch(void* const* d_in, const int* in_sizes, int n_in,
                              void* d_out, int out_size, void* d_ws,
                              size_t ws_size, hipStream_t stream) {
  const float* h    = (const float*)d_in[0];
  const float* rep  = (const float*)d_in[1];
  const int* src    = (const int*)d_in[2];
  const int* dst    = (const int*)d_in[3];
  const float* Wq   = (const float*)d_in[4];
  const float* bq   = (const float*)d_in[5];
  const float* Wk   = (const float*)d_in[6];
  const float* bk   = (const float*)d_in[7];
  const float* Wv   = (const float*)d_in[8];
  const float* bv   = (const float*)d_in[9];
  const float* W0   = (const float*)d_in[10];
  const float* b0   = (const float*)d_in[11];
  const float* Wr   = (const float*)d_in[12];
  const float* br   = (const float*)d_in[13];
  const float* g_ln = (const float*)d_in[14];
  const float* b_ln = (const float*)d_in[15];
  const float* Wms  = (const float*)d_in[16];
  const float* bms  = (const float*)d_in[17];
  const float* Wuas = (const float*)d_in[18];
  float* out = (float*)d_out;

  bf16* ws = (bf16*)d_ws;
  size_t off = 0;
  auto alloc = [&](size_t n) {
    bf16* p = ws + off;
    off += n;
    return p;
  };
  bf16* WqT   = alloc((size_t)NH * NA * ND);       // [h*512][1024]
  bf16* WkT   = alloc((size_t)NH * NA * ND);       // contiguous with WvT!
  bf16* WvT   = alloc((size_t)NH * NA * ND);
  bf16* W0T   = alloc((size_t)NH * NM * NA);       // [h][2048][512]
  bf16* WrT   = alloc((size_t)NH * NRES * NM * NM);// [h*3+j][2048][2048]
  bf16* WmsT  = alloc((size_t)NH * NA * NM);       // [h][512][2048]
  bf16* WuasT = alloc((size_t)ND * NH * NA);       // [1024][1536]
  bf16* Qb    = alloc((size_t)NE * ND);
  bf16* Kb    = alloc((size_t)NE * ND);
  bf16* Qp    = alloc((size_t)NE * NH * NA);       // [E][1536]; reused as cat
  bf16* Kp    = alloc((size_t)NE * NH * NA);       // Kp then Vp contiguous
  bf16* Vp    = alloc((size_t)NE * NH * NA);
  bf16* attn  = alloc((size_t)NH * NE * NA);       // [h][E][512]
  bf16* mbuf3 = alloc((size_t)NH * NE * NM);       // [h][E][2048] (persists)
  bf16* xnb   = alloc((size_t)NE * NM);            // reused per head
  float* cbias = (float*)alloc(2 * (size_t)NH * NA * 2);  // fp32[3072]
  bf16* cat   = Qp;                                // alias: Qp dead after softmax
  if (ws_size < off * sizeof(bf16)) return;  // workspace too small: bail

  const dim3 tb(32, 8);
  transpose_cvt<<<dim3(NA / 32, ND / 32, NH), tb, 0, stream>>>(Wq, WqT, ND, NA);
  transpose_cvt<<<dim3(NA / 32, ND / 32, NH), tb, 0, stream>>>(Wk, WkT, ND, NA);
  transpose_cvt<<<dim3(NA / 32, ND / 32, NH), tb, 0, stream>>>(Wv, WvT, ND, NA);
  transpose_cvt<<<dim3(NM / 32, NA / 32, NH), tb, 0, stream>>>(W0, W0T, NA, NM);
  transpose_cvt<<<dim3(NM / 32, NM / 32, NH * NRES), tb, 0, stream>>>(Wr, WrT,
                                                                      NM, NM);
  transpose_cvt<<<dim3(NA / 32, NM / 32, NH), tb, 0, stream>>>(Wms, WmsT, NM,
                                                               NA);
  transpose_cvt<<<dim3(ND / 32, (NH * NA) / 32, 1), tb, 0, stream>>>(
      Wuas, WuasT, NH * NA, ND);
  concat2_kernel<<<(2 * NH * NA) / 256, 256, 0, stream>>>(bk, bv, cbias,
                                                          NH * NA);

  gather_kernel<<<NE, 256, 0, stream>>>(h, rep, src, dst, Qb, Kb, out);

  // Q projection: N = H*A = 1536
  launch_gemm<0>(stream, Qb, WqT, bq, Qp, nullptr, NE, NH * NA, ND, NH * NA,
                 0, 0);
  // fused K+V projection: N = 3072 (B = [WkT;WvT] contiguous), split output:
  // n<1536 -> Kp[m*1536+n], n>=1536 -> Vp[m*1536+n-1536] = +(NE-1)*1536
  launch_gemm<0>(stream, Kb, WkT, cbias, Kp, nullptr, NE, 2 * NH * NA, ND,
                 NH * NA, NH * NA, (NE - 1) * NH * NA);
  softmax_kernel<<<dim3(NE, NH), 256, 0, stream>>>(Qp, Kp, Vp, attn);

  // per-head MLP chain (R11 structure; outputs persist in mbuf3[h])
  for (int hh = 0; hh < NH; ++hh) {
    const bf16* attn_h = attn + (size_t)hh * NE * NA;
    bf16* mbuf_h = mbuf3 + (size_t)hh * NE * NM;
    launch_gemm<0>(stream, attn_h, W0T + (size_t)hh * NM * NA, b0 + hh * NM,
                   mbuf_h, nullptr, NE, NM, NA, NM, 0, 0);
    for (int j = 0; j < NRES; ++j) {
      const int hj = hh * NRES + j;
      ln_kernel<<<NE, 256, 0, stream>>>(mbuf_h, xnb, g_ln + (size_t)hj * NM,
                                        b_ln + (size_t)hj * NM);
      launch_gemm<1>(stream, xnb, WrT + (size_t)hj * NM * NM, br + hj * NM,
                     mbuf_h, mbuf_h, NE, NM, NM, NM, 0, NM);
    }
  }
  // head-batched Wms: M = 3E -> 1536 blocks
  // cat[e][h*512+n] = mbuf3[h][e][:] @ WmsT[h] + bms[h] + attn[h][e][n]
  launch_gemm<2>(stream, mbuf3, WmsT, bms, cat, attn, NH * NE, NA, NM,
                 NH * NA, NA, NA, ESH, (long long)NA * NM, NA);

  launch_gemm<3>(stream, cat, WuasT, nullptr, out, nullptr, NE, ND, NH * NA,
                 ND, 0, 0);
}

// Round 15
// 2512.042 us; speedup vs baseline: 1.1783x; 1.0150x over previous
//
#include <hip/hip_runtime.h>
#include <hip/hip_bf16.h>
#include <cstdint>
#include <cstddef>

typedef __bf16 bf16;
typedef __bf16 bf16x2 __attribute__((ext_vector_type(2)));
typedef __bf16 bf16x4 __attribute__((ext_vector_type(4)));
typedef __bf16 bf16x8 __attribute__((ext_vector_type(8)));
typedef float f32x4 __attribute__((ext_vector_type(4)));

static_assert(sizeof(bf16x8) == 16, "bf16x8 must be 16B");

#define NE 16384   // E
#define ND 1024    // D
#define NA 512     // A
#define NM 2048    // M
#define NH 3
#define NRES 3
#define ESH 14     // log2(NE)

// ---------------------------------------------------------------------------
// async global->LDS, 16B per lane (wave-uniform LDS base + lane*16 implicit)
__device__ __forceinline__ void async_ld16(const bf16* g, bf16* l) {
  __builtin_amdgcn_global_load_lds(
      (__attribute__((address_space(1))) void*)(void*)g,
      (__attribute__((address_space(3))) void*)(void*)l, 16, 0, 0);
}

template <int N>
__device__ __forceinline__ void vm_wait() {
  asm volatile("s_waitcnt vmcnt(%0)" ::"n"(N) : "memory");
}
__device__ __forceinline__ void lgkm0() {
  asm volatile("s_waitcnt lgkmcnt(0)" ::: "memory");
}
__device__ __forceinline__ void bar() {
  asm volatile("s_barrier" ::: "memory");
}

// ---------------------------------------------------------------------------
// R15 GEMM core: m97-class 128x128 tile, BK=64, 256 threads = 4 waves (2x2,
// 64x64 C each), single-buffered 32 KiB LDS, targeting 4 blocks/CU
// (__launch_bounds__(256,4): reg cap 128/wave in the unified V/A file).
// R14 (3 blocks/CU) confirmed cross-block overlap beats in-block scheduling;
// per-CU audit shows neither MFMA (~621cyc) nor LDS (~832cyc) pipe saturated
// per block-tile (~1400cyc wall) -> residual is vm_wait exposure + barrier
// skew, hidden by MORE co-resident blocks. To fit 128 regs: hold only one
// k-slice of fragments (fa[4]+fb[4], 32 VGPR vs 64) and split the tile:
//   vm_wait(0)+bar -> read ks0 (8) -> MFMA ks0 (16, overlaps ks1 reads)
//   -> read ks1 (8) -> lgkm0+bar (all reads drained; LDS free)
//   -> stage(t+1) (async, overlaps MFMA) -> MFMA ks1 (16)
// Chunk swizzle (verified): logical chunk cc of row r at slot cc^(r&7);
// global source pre-swizzled; row&7 == ln>>3 for every stage issue.
// Block mapping: n-major (bid%nbx) -> A panels L2-resident + XCD swizzle.
// C mapping: m = m0 + wm*64 + mi*16 + (ln>>4)*4 + r;
//            n = n0 + wn*64 + ni*16 + (ln&15)
//
// MODE 0: C_bf16 = acc + bias[n]; optional split-output (fused K/V)
// MODE 1: C_bf16 = addb[m,n] + relu(acc + bias[n])        (residual, in-place)
// MODE 2: C_bf16[m&(NE-1), hidx*coloff+n] = acc+bias[n]+addb[m,n] (-> cat)
// MODE 3: C_f32[m,n] += acc                               (final += Q-K)

template <int MODE>
__global__ __launch_bounds__(256, 4) void gemm_kernel(
    const bf16* __restrict__ A, const bf16* __restrict__ B,
    const float* __restrict__ bias, void* __restrict__ Cv,
    const bf16* __restrict__ addb, int K, int ldc, int coloff, int addld,
    int nbx, int hsh, long long bstr, int bistr) {
  __shared__ bf16 lA[8192];  // [128][64]
  __shared__ bf16 lB[8192];

  // T1: XCD-aware block swizzle (all grids here are multiples of 8)
  const int nwg = gridDim.x;
  int bid = blockIdx.x;
  if ((nwg & 7) == 0) bid = (bid & 7) * (nwg >> 3) + (bid >> 3);
  const int n0 = (bid % nbx) * 128;
  const int m0 = (bid / nbx) * 128;

  // head-batched addressing (used only by the Wms launch)
  const int hidx = hsh ? (m0 >> hsh) : 0;
  if (hsh) {
    B += (size_t)hidx * (size_t)bstr;
    bias += (size_t)hidx * (size_t)bistr;
  }

  const int tid = threadIdx.x;
  const int wv = tid >> 6, ln = tid & 63;
  const int wm = wv >> 1, wn = wv & 1;  // 2x2 waves, each 64x64 of C

  // staging lane geometry: wave wv covers rows r*32 + wv*8 + (ln>>3); slot
  // ln&7 fetches logical chunk (ln&7)^(ln>>3) [pre-swizzled source]
  const int rowq = wv * 8 + (ln >> 3);
  const int colo = ((ln & 7) ^ (ln >> 3)) * 8;
  const bf16* gA = A + (size_t)(m0 + rowq) * K + colo;
  const bf16* gB = B + (size_t)(n0 + rowq) * K + colo;

  auto stage = [&](int t) {
#pragma unroll
    for (int r = 0; r < 4; ++r) {
      async_ld16(gA + (size_t)(r * 32) * K + t * 64,
                 &lA[(r * 32 + wv * 8) * 64]);
      async_ld16(gB + (size_t)(r * 32) * K + t * 64,
                 &lB[(r * 32 + wv * 8) * 64]);
    }
  };

  // fragment read geometry (16x16x32: row = base + l15, k-chunk = ln>>4)
  const int l15 = ln & 15;
  const int aOff = (wm * 64 + l15) * 64;
  const int bOff = (wn * 64 + l15) * 64;
  const int c0 = (ln >> 4) ^ (ln & 7);  // swizzled chunk slot, ks=0

  f32x4 acc[4][4] = {};
  bf16x8 fa[4], fb[4];

  const int nt = K >> 6;

  stage(0);

  for (int t = 0; t < nt; ++t) {
    vm_wait<0>();
    bar();                       // tile t resident + published
    // ---- ks0 reads ----
    {
      const int co = c0 * 8;
#pragma unroll
      for (int i = 0; i < 4; ++i)
        fa[i] = *(const bf16x8*)&lA[aOff + i * 1024 + co];
#pragma unroll
      for (int j = 0; j < 4; ++j)
        fb[j] = *(const bf16x8*)&lB[bOff + j * 1024 + co];
    }
    // ---- MFMA ks0 (compiler inserts lgkm waits on its own reads) ----
    __builtin_amdgcn_s_setprio(1);
#pragma unroll
    for (int i = 0; i < 4; ++i)
#pragma unroll
      for (int j = 0; j < 4; ++j)
        acc[i][j] = __builtin_amdgcn_mfma_f32_16x16x32_bf16(
            fa[i], fb[j], acc[i][j], 0, 0, 0);
    __builtin_amdgcn_s_setprio(0);
    // ---- ks1 reads (registers recycled; WAR on fa/fb orders after MFMA) ----
    {
      const int co = (c0 ^ 4) * 8;
#pragma unroll
      for (int i = 0; i < 4; ++i)
        fa[i] = *(const bf16x8*)&lA[aOff + i * 1024 + co];
#pragma unroll
      for (int j = 0; j < 4; ++j)
        fb[j] = *(const bf16x8*)&lB[bOff + j * 1024 + co];
    }
    lgkm0();
    bar();                       // all waves' reads drained; LDS free
    if (t + 1 < nt) stage(t + 1);  // async, overlaps the MFMAs below
    __builtin_amdgcn_s_setprio(1);
#pragma unroll
    for (int i = 0; i < 4; ++i)
#pragma unroll
      for (int j = 0; j < 4; ++j)
        acc[i][j] = __builtin_amdgcn_mfma_f32_16x16x32_bf16(
            fa[i], fb[j], acc[i][j], 0, 0, 0);
    __builtin_amdgcn_s_setprio(0);
  }

  // epilogue: 16x16 C/D layout col = ln&15, row = (ln>>4)*4 + r
  const int r4 = (ln >> 4) * 4;
  const int nbase = n0 + wn * 64 + l15;
#pragma unroll
  for (int mi = 0; mi < 4; ++mi) {
#pragma unroll
    for (int r = 0; r < 4; ++r) {
      const int m = m0 + wm * 64 + mi * 16 + r4 + r;
#pragma unroll
      for (int ni = 0; ni < 4; ++ni) {
        const int n = nbase + ni * 16;
        float v = acc[mi][ni][r];
        if constexpr (MODE != 3) v += bias[n];
        if constexpr (MODE == 0) {
          size_t idx = (size_t)m * ldc + n;
          if (coloff && n >= coloff) idx += (size_t)addld;  // split output
          ((bf16*)Cv)[idx] = (bf16)v;
        } else if constexpr (MODE == 1) {
          float prev = (float)addb[(size_t)m * addld + n];
          ((bf16*)Cv)[(size_t)m * ldc + n] = (bf16)(prev + fmaxf(v, 0.f));
        } else if constexpr (MODE == 2) {
          v += (float)addb[(size_t)m * addld + n];
          const int mloc = hsh ? (m & ((1 << hsh) - 1)) : m;
          ((bf16*)Cv)[(size_t)mloc * ldc + hidx * coloff + n] = (bf16)v;
        } else {
          float* C = (float*)Cv;
          const size_t idx = (size_t)m * ldc + n;
          C[idx] = C[idx] + v;
        }
      }
    }
  }
}

template <int MODE>
static void launch_gemm(hipStream_t s, const bf16* A, const bf16* B,
                        const float* bias, void* C, const bf16* addb, int M,
                        int N, int K, int ldc, int coloff, int addld,
                        int hsh = 0, long long bstr = 0, int bistr = 0) {
  const int nbx = N / 128;
  gemm_kernel<MODE><<<dim3(nbx * (M / 128)), 256, 0, s>>>(
      A, B, bias, C, addb, K, ldc, coloff, addld, nbx, hsh, bstr, bistr);
}

// ---------------------------------------------------------------------------
// fp32 [K,N] -> bf16 [N,K] transpose-convert, 32x32 tiles, batched over z
__global__ void transpose_cvt(const float* __restrict__ src,
                              bf16* __restrict__ dst, int K, int N) {
  __shared__ float t[32][33];
  const size_t zo = (size_t)blockIdx.z * K * N;
  src += zo;
  dst += zo;
  const int n = blockIdx.x * 32 + threadIdx.x;
  const int kb = blockIdx.y * 32;
#pragma unroll
  for (int i = 0; i < 4; ++i) {
    const int k = kb + threadIdx.y + i * 8;
    t[threadIdx.y + i * 8][threadIdx.x] = src[(size_t)k * N + n];
  }
  __syncthreads();
#pragma unroll
  for (int i = 0; i < 4; ++i) {
    const int nn = blockIdx.x * 32 + threadIdx.y + i * 8;
    dst[(size_t)nn * K + kb + threadIdx.x] =
        (bf16)t[threadIdx.x][threadIdx.y + i * 8];
  }
}

// ---------------------------------------------------------------------------
// concat two fp32 vectors (bk|bv) -> dst
__global__ void concat2_kernel(const float* __restrict__ a,
                               const float* __restrict__ b,
                               float* __restrict__ dst, int na) {
  const int i = blockIdx.x * 256 + threadIdx.x;
  dst[i] = (i < na) ? a[i] : b[i - na];
}

// ---------------------------------------------------------------------------
// Q = normalize(h)[src], K = rep[dst]; emit bf16 Q,K and fp32 (Q-K) -> d_out
__global__ __launch_bounds__(256) void gather_kernel(
    const float* __restrict__ h, const float* __restrict__ rep,
    const int* __restrict__ src, const int* __restrict__ dst,
    bf16* __restrict__ Qb, bf16* __restrict__ Kb, float* __restrict__ qk) {
  __shared__ float sm[4];
  const int e = blockIdx.x, tid = threadIdx.x;
  const int sr = src[e], dr = dst[e];
  const float4 hv = ((const float4*)(h + (size_t)sr * ND))[tid];
  float ss = hv.x * hv.x + hv.y * hv.y + hv.z * hv.z + hv.w * hv.w;
#pragma unroll
  for (int o = 32; o > 0; o >>= 1) ss += __shfl_down(ss, o, 64);
  if ((tid & 63) == 0) sm[tid >> 6] = ss;
  __syncthreads();
  const float tot = sm[0] + sm[1] + sm[2] + sm[3];
  const float inv = 1.f / fmaxf(sqrtf(tot), 1e-12f);
  const float4 rv = ((const float4*)(rep + (size_t)dr * ND))[tid];
  const float q0 = hv.x * inv, q1 = hv.y * inv, q2 = hv.z * inv,
              q3 = hv.w * inv;
  const size_t base = (size_t)e * ND + tid * 4;
  bf16x4 qv;
  qv[0] = (bf16)q0; qv[1] = (bf16)q1; qv[2] = (bf16)q2; qv[3] = (bf16)q3;
  *(bf16x4*)(Qb + base) = qv;
  bf16x4 kv;
  kv[0] = (bf16)rv.x; kv[1] = (bf16)rv.y; kv[2] = (bf16)rv.z;
  kv[3] = (bf16)rv.w;
  *(bf16x4*)(Kb + base) = kv;
  *(float4*)(qk + base) =
      make_float4(q0 - rv.x, q1 - rv.y, q2 - rv.z, q3 - rv.w);
}

// ---------------------------------------------------------------------------
// attn = softmax(Qp*Kp/sqrt(A), axis=-1) * Vp   (per row of 512)
// Qp/Kp/Vp are [E][H*A]; attn out is [h][E][A]. grid = (E, H).
__global__ __launch_bounds__(256) void softmax_kernel(
    const bf16* __restrict__ Qp, const bf16* __restrict__ Kp,
    const bf16* __restrict__ Vp, bf16* __restrict__ attn) {
  __shared__ float sm[4];
  const int tid = threadIdx.x;
  const int e = blockIdx.x, hh = blockIdx.y;
  const size_t base = (size_t)e * (NH * NA) + (size_t)hh * NA + 2 * tid;
  const bf16x2 q = *(const bf16x2*)(Qp + base);
  const bf16x2 k = *(const bf16x2*)(Kp + base);
  const bf16x2 v = *(const bf16x2*)(Vp + base);
  const float sc = 0.044194173824159216f;  // 1/sqrt(512)
  const float s0 = (float)q[0] * (float)k[0] * sc;
  const float s1 = (float)q[1] * (float)k[1] * sc;
  float mx = fmaxf(s0, s1);
#pragma unroll
  for (int o = 32; o > 0; o >>= 1) mx = fmaxf(mx, __shfl_down(mx, o, 64));
  if ((tid & 63) == 0) sm[tid >> 6] = mx;
  __syncthreads();
  mx = fmaxf(fmaxf(sm[0], sm[1]), fmaxf(sm[2], sm[3]));
  __syncthreads();
  const float p0 = expf(s0 - mx), p1 = expf(s1 - mx);
  float ssum = p0 + p1;
#pragma unroll
  for (int o = 32; o > 0; o >>= 1) ssum += __shfl_down(ssum, o, 64);
  if ((tid & 63) == 0) sm[tid >> 6] = ssum;
  __syncthreads();
  const float inv = 1.f / (sm[0] + sm[1] + sm[2] + sm[3]);
  bf16x2 r;
  r[0] = (bf16)(p0 * inv * (float)v[0]);
  r[1] = (bf16)(p1 * inv * (float)v[1]);
  const size_t obase = (size_t)hh * NE * NA + (size_t)e * NA + 2 * tid;
  *(bf16x2*)(attn + obase) = r;
}

// ---------------------------------------------------------------------------
// y = LN(x) * g + b over rows of 2048
__global__ __launch_bounds__(256) void ln_kernel(const bf16* __restrict__ x,
                                                 bf16* __restrict__ y,
                                                 const float* __restrict__ g,
                                                 const float* __restrict__ b) {
  __shared__ float sm[8];
  const int tid = threadIdx.x;
  const size_t base = (size_t)blockIdx.x * NM + tid * 8;
  const bf16x8 xv = *(const bf16x8*)(x + base);
  float xf[8], s = 0.f, ss = 0.f;
#pragma unroll
  for (int i = 0; i < 8; ++i) {
    xf[i] = (float)xv[i];
    s += xf[i];
    ss += xf[i] * xf[i];
  }
#pragma unroll
  for (int o = 32; o > 0; o >>= 1) {
    s += __shfl_down(s, o, 64);
    ss += __shfl_down(ss, o, 64);
  }
  if ((tid & 63) == 0) {
    sm[tid >> 6] = s;
    sm[4 + (tid >> 6)] = ss;
  }
  __syncthreads();
  s = sm[0] + sm[1] + sm[2] + sm[3];
  ss = sm[4] + sm[5] + sm[6] + sm[7];
  const float mu = s * (1.f / NM);
  const float var = ss * (1.f / NM) - mu * mu;
  const float rstd = rsqrtf(fmaxf(var, 0.f) + 1e-5f);
  const int c0 = tid * 8;
  bf16x8 yv;
#pragma unroll
  for (int i = 0; i < 8; ++i)
    yv[i] = (bf16)((xf[i] - mu) * rstd * g[c0 + i] + b[c0 + i]);
  *(bf16x8*)(y + base) = yv;
}

// ---------------------------------------------------------------------------
extern "C" void kernel_launch(void* const* d_in, const int* in_sizes, int n_in,
                              void* d_out, int out_size, void* d_ws,
                              size_t ws_size, hipStream_t stream) {
  const float* h    = (const float*)d_in[0];
  const float* rep  = (const float*)d_in[1];
  const int* src    = (const int*)d_in[2];
  const int* dst    = (const int*)d_in[3];
  const float* Wq   = (const float*)d_in[4];
  const float* bq   = (const float*)d_in[5];
  const float* Wk   = (const float*)d_in[6];
  const float* bk   = (const float*)d_in[7];
  const float* Wv   = (const float*)d_in[8];
  const float* bv   = (const float*)d_in[9];
  const float* W0   = (const float*)d_in[10];
  const float* b0   = (const float*)d_in[11];
  const float* Wr   = (const float*)d_in[12];
  const float* br   = (const float*)d_in[13];
  const float* g_ln = (const float*)d_in[14];
  const float* b_ln = (const float*)d_in[15];
  const float* Wms  = (const float*)d_in[16];
  const float* bms  = (const float*)d_in[17];
  const float* Wuas = (const float*)d_in[18];
  float* out = (float*)d_out;

  bf16* ws = (bf16*)d_ws;
  size_t off = 0;
  auto alloc = [&](size_t n) {
    bf16* p = ws + off;
    off += n;
    return p;
  };
  bf16* WqT   = alloc((size_t)NH * NA * ND);       // [h*512][1024]
  bf16* WkT   = alloc((size_t)NH * NA * ND);       // contiguous with WvT!
  bf16* WvT   = alloc((size_t)NH * NA * ND);
  bf16* W0T   = alloc((size_t)NH * NM * NA);       // [h][2048][512]
  bf16* WrT   = alloc((size_t)NH * NRES * NM * NM);// [h*3+j][2048][2048]
  bf16* WmsT  = alloc((size_t)NH * NA * NM);       // [h][512][2048]
  bf16* WuasT = alloc((size_t)ND * NH * NA);       // [1024][1536]
  bf16* Qb    = alloc((size_t)NE * ND);
  bf16* Kb    = alloc((size_t)NE * ND);
  bf16* Qp    = alloc((size_t)NE * NH * NA);       // [E][1536]; reused as cat
  bf16* Kp    = alloc((size_t)NE * NH * NA);       // Kp then Vp contiguous
  bf16* Vp    = alloc((size_t)NE * NH * NA);
  bf16* attn  = alloc((size_t)NH * NE * NA);       // [h][E][512]
  bf16* mbuf3 = alloc((size_t)NH * NE * NM);       // [h][E][2048] (persists)
  bf16* xnb   = alloc((size_t)NE * NM);            // reused per head
  float* cbias = (float*)alloc(2 * (size_t)NH * NA * 2);  // fp32[3072]
  bf16* cat   = Qp;                                // alias: Qp dead after softmax
  if (ws_size < off * sizeof(bf16)) return;  // workspace too small: bail

  const dim3 tb(32, 8);
  transpose_cvt<<<dim3(NA / 32, ND / 32, NH), tb, 0, stream>>>(Wq, WqT, ND, NA);
  transpose_cvt<<<dim3(NA / 32, ND / 32, NH), tb, 0, stream>>>(Wk, WkT, ND, NA);
  transpose_cvt<<<dim3(NA / 32, ND / 32, NH), tb, 0, stream>>>(Wv, WvT, ND, NA);
  transpose_cvt<<<dim3(NM / 32, NA / 32, NH), tb, 0, stream>>>(W0, W0T, NA, NM);
  transpose_cvt<<<dim3(NM / 32, NM / 32, NH * NRES), tb, 0, stream>>>(Wr, WrT,
                                                                      NM, NM);
  transpose_cvt<<<dim3(NA / 32, NM / 32, NH), tb, 0, stream>>>(Wms, WmsT, NM,
                                                               NA);
  transpose_cvt<<<dim3(ND / 32, (NH * NA) / 32, 1), tb, 0, stream>>>(
      Wuas, WuasT, NH * NA, ND);
  concat2_kernel<<<(2 * NH * NA) / 256, 256, 0, stream>>>(bk, bv, cbias,
                                                          NH * NA);

  gather_kernel<<<NE, 256, 0, stream>>>(h, rep, src, dst, Qb, Kb, out);

  // Q projection: N = H*A = 1536
  launch_gemm<0>(stream, Qb, WqT, bq, Qp, nullptr, NE, NH * NA, ND, NH * NA,
                 0, 0);
  // fused K+V projection: N = 3072 (B = [WkT;WvT] contiguous), split output:
  // n<1536 -> Kp[m*1536+n], n>=1536 -> Vp[m*1536+n-1536] = +(NE-1)*1536
  launch_gemm<0>(stream, Kb, WkT, cbias, Kp, nullptr, NE, 2 * NH * NA, ND,
                 NH * NA, NH * NA, (NE - 1) * NH * NA);
  softmax_kernel<<<dim3(NE, NH), 256, 0, stream>>>(Qp, Kp, Vp, attn);

  // per-head MLP chain (outputs persist in mbuf3[h])
  for (int hh = 0; hh < NH; ++hh) {
    const bf16* attn_h = attn + (size_t)hh * NE * NA;
    bf16* mbuf_h = mbuf3 + (size_t)hh * NE * NM;
    launch_gemm<0>(stream, attn_h, W0T + (size_t)hh * NM * NA, b0 + hh * NM,
                   mbuf_h, nullptr, NE, NM, NA, NM, 0, 0);
    for (int j = 0; j < NRES; ++j) {
      const int hj = hh * NRES + j;
      ln_kernel<<<NE, 256, 0, stream>>>(mbuf_h, xnb, g_ln + (size_t)hj * NM,
                                        b_ln + (size_t)hj * NM);
      launch_gemm<1>(stream, xnb, WrT + (size_t)hj * NM * NM, br + hj * NM,
                     mbuf_h, mbuf_h, NE, NM, NM, NM, 0, NM);
    }
  }
  // head-batched Wms: M = 3E -> 1536 blocks
  // cat[e][h*512+n] = mbuf3[h][e][:] @ WmsT[h] + bms[h] + attn[h][e][n]
  launch_gemm<2>(stream, mbuf3, WmsT, bms, cat, attn, NH * NE, NA, NM,
                 NH * NA, NA, NA, ESH, (long long)NA * NM, NA);

  launch_gemm<3>(stream, cat, WuasT, nullptr, out, nullptr, NE, ND, NH * NA,
                 ND, 0, 0);
}